// Round 6
// baseline (257.359 us; speedup 1.0000x reference)
//
#include <hip/hip_runtime.h>
#include <math.h>

// Quantized causal attention on int8 MFMA — R12.
// R11 post-mortem: best total (243.3us); attn_main 120us at 2 blocks/CU.
// Monolithic kernel can't exceed 2 blocks: P1 live state (sarr,m/l/mn) +
// P2 live state (outa[32], consts) share one allocation; forced caps spill
// (R7/R9), relaxed caps hit 256-reg budget (R8). R12 splits by phase:
//  - attn_p1 (stats): 29KB LDS, ~100 live regs -> (256,4), 4 blocks/CU.
//    Writes mx/den/mn (64x3 floats/block) to ws.
//  - attn_p2 (requant+PV): 43KB LDS -> (256,3); qb NOT hoisted (read per-cb
//    from q8s) to fit 170 regs spill-free. Re-stages Q (+16MB fetch ~ 3us).
// prep_v / prep_k unchanged from R11.
// Tripwires: p1 WRITE ~1MB, p2 WRITE ~33MB (ballooning = spills);
// p1+p2 >= 120us refutes the split -> revert to R11, attack bank conflicts.

#define S_LEN 2048
#define BATCH 2
#define NH    16
#define HD    128
#define RSTR  4096   // floats between seq positions
#define SCALE2 (0.08838834764831845f * 1.4426950408889634f)   // (1/sqrt(128))/ln2
#define EXP2F(x) __builtin_amdgcn_exp2f(x)

typedef int v4i __attribute__((ext_vector_type(4)));
#define MFMA16(a,b,c) __builtin_amdgcn_mfma_i32_16x16x64_i8((a),(b),(c),0,0,0)

// ws byte offsets (~17.25 MB total)
#define WS_K8   0u
#define WS_V8T  (8u*1024u*1024u)
#define WS_SK   (16u*1024u*1024u)
#define WS_GSV  (WS_SK  + 256u*1024u)
#define WS_STMX (WS_GSV + 256u*1024u)
#define WS_STDN (WS_STMX + 256u*1024u)
#define WS_STMN (WS_STDN + 256u*1024u)

__device__ __forceinline__ int sbsum(unsigned p) {
    return (int)(signed char)(p) + (int)(signed char)(p>>8)
         + (int)(signed char)(p>>16) + (int)(signed char)(p>>24);
}

// ---- prep_k: streaming float->int8 pack of K + per-token sums SKs ----
__global__ __launch_bounds__(256) void prep_k(const float* __restrict__ K,
                                              signed char* __restrict__ K8,
                                              float* __restrict__ SKs)
{
    const int base = blockIdx.x*2048 + threadIdx.x;   // 1024 blocks x 256 x 8
    #pragma unroll
    for (int rep = 0; rep < 8; ++rep) {
        int idx = base + rep*256;                     // float4 index
        float4 x = *(const float4*)(K + (size_t)idx*4);
        int a=(int)x.x, b=(int)x.y, c=(int)x.z, d=(int)x.w;
        ((int*)K8)[idx] = (a&255)|((b&255)<<8)|((c&255)<<16)|((d&255)<<24);
        float s = x.x + x.y + x.z + x.w;
        #pragma unroll
        for (int off = 16; off >= 1; off >>= 1) s += __shfl_xor(s, off);
        if ((threadIdx.x & 31) == 0) SKs[idx >> 5] = s;
    }
}

// ---- prep_v: V transpose to [bh][d][t] int8 + GSV group sums ----
__global__ __launch_bounds__(256) void prep_v(const float* __restrict__ V,
                                              signed char* __restrict__ V8T,
                                              float* __restrict__ GSV)
{
    __shared__ int v8i[128*33];
    const int tid = threadIdx.x;
    const int bid = blockIdx.x;                 // 512 blocks
    const int bh = bid & 31, ck = bid >> 5;     // ck = 128-t chunk = v-group
    const int b = bh >> 4, h = bh & 15;
    const int t0 = ck * 128;
    const int boff = b*2048 + h*128;
    #pragma unroll
    for (int it = 0; it < 16; ++it) {
        int idx = tid + it*256;
        int t = idx >> 5, dw = idx & 31;
        float4 x = *(const float4*)(V + (size_t)(t0+t)*RSTR + boff + 4*dw);
        int a=(int)x.x, b2=(int)x.y, c=(int)x.z, d=(int)x.w;
        v8i[t*33 + dw] = (a&255)|((b2&255)<<8)|((c&255)<<16)|((d&255)<<24);
    }
    __syncthreads();
    #pragma unroll
    for (int it = 0; it < 4; ++it) {
        int j = tid + it*256;
        int tg = j & 31, dw = j >> 5;
        unsigned r0 = (unsigned)v8i[(4*tg+0)*33 + dw];
        unsigned r1 = (unsigned)v8i[(4*tg+1)*33 + dw];
        unsigned r2 = (unsigned)v8i[(4*tg+2)*33 + dw];
        unsigned r3 = (unsigned)v8i[(4*tg+3)*33 + dw];
        unsigned x01 = __builtin_amdgcn_perm(r1, r0, 0x05010400u);
        unsigned x23 = __builtin_amdgcn_perm(r3, r2, 0x05010400u);
        unsigned y01 = __builtin_amdgcn_perm(r1, r0, 0x07030602u);
        unsigned y23 = __builtin_amdgcn_perm(r3, r2, 0x07030602u);
        unsigned p[4];
        p[0] = __builtin_amdgcn_perm(x23, x01, 0x05040100u);
        p[1] = __builtin_amdgcn_perm(x23, x01, 0x07060302u);
        p[2] = __builtin_amdgcn_perm(y23, y01, 0x05040100u);
        p[3] = __builtin_amdgcn_perm(y23, y01, 0x07060302u);
        int s[4];
        #pragma unroll
        for (int jj = 0; jj < 4; ++jj) {
            int d = 4*dw + jj;
            *(int*)(V8T + ((size_t)bh*128 + d)*2048 + t0 + 4*tg) = (int)p[jj];
            s[jj] = sbsum(p[jj]);
        }
        #pragma unroll
        for (int off = 1; off < 32; off <<= 1) {
            #pragma unroll
            for (int jj = 0; jj < 4; ++jj) s[jj] += __shfl_xor(s[jj], off);
        }
        if (tg == 0) {
            #pragma unroll
            for (int jj = 0; jj < 4; ++jj)
                GSV[((size_t)bh*16 + ck)*128 + 4*dw + jj] = (float)s[jj];
        }
    }
}

// ---- Phase 1 kernel: softmax stats (mx, den, mn per q row) ----
__global__ __launch_bounds__(256, 4) void attn_p1(
    const float* __restrict__ Q, const signed char* __restrict__ K8,
    const float* __restrict__ QMN, const float* __restrict__ QSC,
    const float* __restrict__ KMN, const float* __restrict__ KSC,
    const float* __restrict__ SKs, const int* __restrict__ CAUSAL,
    float* __restrict__ STmx, float* __restrict__ STden, float* __restrict__ STmn)
{
    __shared__ __align__(16) signed char q8s[64*144];   // [q][d] int8
    __shared__ __align__(16) signed char k8s[128*144];  // [t][d] int8
    __shared__ float rs_c1[64], rs_c2[64], rs_c3[64];
    __shared__ float ktA[128], ktB[128], ktC[128];      // ks*S2, km*S2, sk8

    const int tid  = threadIdx.x;
    const int w    = tid >> 6;
    const int lane = tid & 63;
    const int n    = lane & 15;
    const int quad = lane >> 4;
    const int bhi  = blockIdx.x & 31;
    const int qt   = 31 - (int)(blockIdx.x >> 5);   // heavy tiles first
    const int causal = *CAUSAL;
    const int s0   = qt * 64;
    const int boff = (bhi >> 4)*2048 + (bhi & 15)*128;
    const v4i vzero = {0,0,0,0};
    const v4i ones  = {0x01010101,0x01010101,0x01010101,0x01010101};

    // ---- stage Q tile (float -> int8 LDS) + per-row consts ----
    #pragma unroll
    for (int it = 0; it < 8; ++it) {
        int idx = tid + it*256;
        int row = idx >> 5, d4 = (idx & 31) << 2;
        float4 x = *(const float4*)(Q + (size_t)(s0+row)*RSTR + boff + d4);
        int a=(int)x.x, b2=(int)x.y, c=(int)x.z, d=(int)x.w;
        *(int*)(q8s + row*144 + d4) = (a&255)|((b2&255)<<8)|((c&255)<<16)|((d&255)<<24);
    }
    if (tid < 64) {
        int si = (s0 + tid)*32 + bhi;
        rs_c1[tid] = QSC[si]; rs_c2[tid] = QMN[si];
    }
    __syncthreads();

    const int kt_end = causal ? ((s0 + 63) >> 7) : 15;

    v4i a0p = *(const v4i*)(q8s + (16*w + n)*144 + 16*quad);
    v4i a1p = *(const v4i*)(q8s + (16*w + n)*144 + 64 + 16*quad);

    // Q token sums via one MFMA-ones pair -> rs_c3
    {
        v4i qsum = MFMA16(a0p, ones, vzero);
        qsum = MFMA16(a1p, ones, qsum);
        if (n == 0) {
            #pragma unroll
            for (int r = 0; r < 4; ++r) {
                int qq = 16*w + 4*quad + r;
                rs_c3[qq] = fmaf(rs_c1[qq], (float)qsum[r], 128.0f*rs_c2[qq]);
            }
        }
    }
    __syncthreads();

    float c1r[4], c2r[4], c3r[4]; int qgr[4];
    #pragma unroll
    for (int r = 0; r < 4; ++r) {
        int qq = 16*w + 4*quad + r;
        c1r[r] = rs_c1[qq]; c2r[r] = rs_c2[qq]; c3r[r] = rs_c3[qq];
        qgr[r] = s0 + qq;
    }

    float m[4], l[4], mn[4];
    #pragma unroll
    for (int r = 0; r < 4; ++r) { m[r] = -INFINITY; l[r] = 0.f; mn[r] = INFINITY; }

#define P1_TILE(MASKED)                                                          \
  do {                                                                           \
    const int t0g = kt * 128;                                                    \
    __syncthreads();                                                             \
    _Pragma("unroll")                                                            \
    for (int it = 0; it < 4; ++it) {                                             \
        int idx = tid + it*256;                                                  \
        int trow = idx >> 3, doff = (idx & 7) << 4;                              \
        *(uint4*)(k8s + trow*144 + doff) =                                       \
            *(const uint4*)(K8 + ((size_t)(t0g+trow)*32 + bhi)*128 + doff);      \
    }                                                                            \
    if (tid < 128) {                                                             \
        int si = (t0g + tid)*32 + bhi;                                           \
        ktA[tid] = KSC[si]*SCALE2; ktB[tid] = KMN[si]*SCALE2; ktC[tid] = SKs[si];\
    }                                                                            \
    __syncthreads();                                                             \
    float tmax[4], sarr[8][4];                                                   \
    _Pragma("unroll")                                                            \
    for (int r = 0; r < 4; ++r) tmax[r] = -INFINITY;                             \
    _Pragma("unroll")                                                            \
    for (int tb = 0; tb < 8; ++tb) {                                             \
        v4i b0 = *(const v4i*)(k8s + (16*tb + n)*144 + 16*quad);                 \
        v4i b1 = *(const v4i*)(k8s + (16*tb + n)*144 + 64 + 16*quad);            \
        v4i acc = MFMA16(a0p, b0, vzero);                                        \
        acc = MFMA16(a1p, b1, acc);                                              \
        int tl = 16*tb + n;                                                      \
        float kA = ktA[tl], kB = ktB[tl], kC = ktC[tl];                          \
        _Pragma("unroll")                                                        \
        for (int r = 0; r < 4; ++r) {                                            \
            float Sf = (float)acc[r];                                            \
            float sv = fmaf(kA, fmaf(c1r[r], Sf, c2r[r]*kC), kB*c3r[r]);         \
            if (MASKED) sv = (t0g + tl > qgr[r]) ? -INFINITY : sv;               \
            sarr[tb][r] = sv;                                                    \
            tmax[r] = fmaxf(tmax[r], sv);                                        \
            mn[r] = fminf(mn[r], sv);                                            \
        }                                                                        \
    }                                                                            \
    _Pragma("unroll")                                                            \
    for (int r = 0; r < 4; ++r) {                                                \
        float mm = fmaxf(m[r], tmax[r]);                                         \
        if (mm > -INFINITY) {                                                    \
            float e0 = EXP2F(sarr[0][r]-mm) + EXP2F(sarr[1][r]-mm);              \
            float e1 = EXP2F(sarr[2][r]-mm) + EXP2F(sarr[3][r]-mm);              \
            float e2 = EXP2F(sarr[4][r]-mm) + EXP2F(sarr[5][r]-mm);              \
            float e3 = EXP2F(sarr[6][r]-mm) + EXP2F(sarr[7][r]-mm);              \
            l[r] = fmaf(l[r], EXP2F(m[r]-mm), (e0+e1)+(e2+e3));                  \
            m[r] = mm;                                                           \
        }                                                                        \
    }                                                                            \
  } while (0)

    {
        int kt;
        for (kt = 0; kt < kt_end; ++kt) P1_TILE(false);
        kt = kt_end;
        if (causal) P1_TILE(true); else P1_TILE(false);
    }

    // reduce stats across the 16 col-lanes; write to global
    #pragma unroll
    for (int r = 0; r < 4; ++r) {
        #pragma unroll
        for (int off = 1; off < 16; off <<= 1) {
            float m2 = __shfl_xor(m[r], off);
            float l2 = __shfl_xor(l[r], off);
            float n2 = __shfl_xor(mn[r], off);
            float mm = fmaxf(m[r], m2);
            if (mm > -INFINITY) l[r] = l[r]*EXP2F(m[r]-mm) + l2*EXP2F(m2-mm);
            m[r] = mm;
            mn[r] = fminf(mn[r], n2);
        }
        if (n == 0) {
            int qq = 16*w + 4*quad + r;
            int gi = (int)blockIdx.x*64 + qq;
            STmx[gi] = m[r]; STden[gi] = l[r]; STmn[gi] = mn[r];
        }
    }
}

// ---- Phase 2 kernel: requant + PV + epilogue ----
__global__ __launch_bounds__(256, 3) void attn_p2(
    const float* __restrict__ Q,
    const signed char* __restrict__ K8, const signed char* __restrict__ V8T,
    const float* __restrict__ QMN, const float* __restrict__ QSC,
    const float* __restrict__ KMN, const float* __restrict__ KSC,
    const float* __restrict__ VMN, const float* __restrict__ VSC,
    const float* __restrict__ SKs, const float* __restrict__ GSV,
    const float* __restrict__ STmx, const float* __restrict__ STden,
    const float* __restrict__ STmn,
    const int* __restrict__ CAUSAL, float* __restrict__ OUT)
{
    __shared__ __align__(16) signed char q8s[64*144];   // [q][d] int8
    __shared__ __align__(16) signed char v8s[128*144];  // [d][t] int8 (transposed)
    __shared__ __align__(16) signed char pcs[64*144];   // [q][t] code' int8
    __shared__ float rs_c1[64], rs_c2[64], rs_c3[64];
    __shared__ float rs_mx[64], rs_u1[64], rs_w1[64], rs_psc[64], rs_pmn[64];
    __shared__ float ktA[128], ktB[128], ktC[128];      // ks*S2, km*S2, sk8
    __shared__ float vsA[128], vsB[128];                // vs, vm (current group)
    __shared__ float vsumL[128], cgsL[128];             // VSUM / CGS row

    const int tid  = threadIdx.x;
    const int w    = tid >> 6;
    const int lane = tid & 63;
    const int n    = lane & 15;
    const int quad = lane >> 4;
    const int bhi  = blockIdx.x & 31;
    const int qt   = 31 - (int)(blockIdx.x >> 5);   // heavy tiles first
    const int b    = bhi >> 4, h = bhi & 15;
    const int causal = *CAUSAL;
    const int s0   = qt * 64;
    const int boff = b*2048 + h*128;
    const v4i vzero = {0,0,0,0};
    const v4i ones  = {0x01010101,0x01010101,0x01010101,0x01010101};

    const int kt_end = causal ? ((s0 + 63) >> 7) : 15;

    // ---- stage Q tile + per-row consts + VSUM/CGS ----
    #pragma unroll
    for (int it = 0; it < 8; ++it) {
        int idx = tid + it*256;
        int row = idx >> 5, d4 = (idx & 31) << 2;
        float4 x = *(const float4*)(Q + (size_t)(s0+row)*RSTR + boff + d4);
        int a=(int)x.x, b2=(int)x.y, c=(int)x.z, d=(int)x.w;
        *(int*)(q8s + row*144 + d4) = (a&255)|((b2&255)<<8)|((c&255)<<16)|((d&255)<<24);
    }
    if (tid < 64) {
        int si = (s0 + tid)*32 + bhi;
        rs_c1[tid] = QSC[si]; rs_c2[tid] = QMN[si];
    } else if (tid >= 128) {
        int d = tid - 128;
        float vsum = 0.f, cgs = 0.f;
        #pragma unroll
        for (int g = 0; g < 16; ++g) {
            float gs = GSV[((size_t)bhi*16 + g)*128 + d];
            int vi = ((g*BATCH + b)*NH + h)*HD + d;
            float vs = VSC[vi], vm = VMN[vi];
            vsum = fmaf(vs, gs, fmaf(128.0f, vm, vsum));
            if (g <= kt_end) cgs = fmaf(128.0f*vs, gs, fmaf(16384.0f, vm, cgs));
        }
        vsumL[d] = vsum; cgsL[d] = cgs;
    }
    __syncthreads();

    // qsum MFMA -> rs_c3 ; stats -> derived per-q constants
    {
        v4i a0p = *(const v4i*)(q8s + (16*w + n)*144 + 16*quad);
        v4i a1p = *(const v4i*)(q8s + (16*w + n)*144 + 64 + 16*quad);
        v4i qsum = MFMA16(a0p, ones, vzero);
        qsum = MFMA16(a1p, ones, qsum);
        if (n == 0) {
            #pragma unroll
            for (int r = 0; r < 4; ++r) {
                int qq = 16*w + 4*quad + r;
                rs_c3[qq] = fmaf(rs_c1[qq], (float)qsum[r], 128.0f*rs_c2[qq]);
            }
        }
    }
    if (tid < 64) {
        int gi = (int)blockIdx.x*64 + tid;
        float mx = STmx[gi], den = STden[gi], mnv = STmn[gi];
        float invd = 1.0f/den;
        int s = s0 + tid;
        bool hasmask = (causal != 0) && (s < S_LEN-1);
        float pmin = hasmask ? 0.0f : EXP2F(mnv - mx)*invd;
        float psc  = (invd - pmin)/255.0f + 1e-12f;
        float ipsc = 1.0f/psc;
        rs_mx[tid] = mx;
        rs_u1[tid] = invd*ipsc; rs_w1[tid] = -pmin*ipsc;
        rs_psc[tid] = psc; rs_pmn[tid] = pmin;
    }
    __syncthreads();

    // ---- hoist per-q scalars (Q B-fragments stay in LDS) ----
    float qc1[4], qc2[4], qc3[4], qmxn[4], qu1[4], qw1[4];
    int qgq[4];
    #pragma unroll
    for (int cb = 0; cb < 4; ++cb) {
        int qcol = 16*cb + n;
        qc1[cb] = rs_c1[qcol]; qc2[cb] = rs_c2[qcol]; qc3[cb] = rs_c3[qcol];
        qmxn[cb] = -rs_mx[qcol]; qu1[cb] = rs_u1[qcol]; qw1[cb] = rs_w1[qcol];
        qgq[cb] = s0 + qcol;
    }

    float outa[4][8];
    #pragma unroll
    for (int r = 0; r < 4; ++r)
        #pragma unroll
        for (int db = 0; db < 8; ++db) outa[r][db] = 0.f;

#define P2_TILE(MASKED)                                                          \
  do {                                                                           \
    const int t0g = kt * 128;                                                    \
    __syncthreads();   /* previous PV reads of v8s/pcs done */                   \
    _Pragma("unroll")                                                            \
    for (int it = 0; it < 4; ++it) {                                             \
        int idx = tid + it*256;                                                  \
        int trow = idx >> 3, doff = (idx & 7) << 4;                              \
        *(uint4*)(v8s + trow*144 + doff) =                                       \
            *(const uint4*)(V8T + ((size_t)bhi*128 + trow)*2048 + t0g + doff);   \
    }                                                                            \
    if (tid < 128) {                                                             \
        int si = (t0g + tid)*32 + bhi;                                           \
        ktA[tid] = KSC[si]*SCALE2; ktB[tid] = KMN[si]*SCALE2; ktC[tid] = SKs[si];\
    } else {                                                                     \
        int d = tid - 128;                                                       \
        int vi = ((kt*BATCH + b)*NH + h)*HD + d;                                 \
        vsA[d] = VSC[vi]; vsB[d] = VMN[vi];                                      \
    }                                                                            \
    __syncthreads();                                                             \
    _Pragma("unroll")                                                            \
    for (int rb = 0; rb < 2; ++rb) {                                             \
        int trow = 32*w + 16*rb;                                                 \
        const signed char* kp = K8 + ((size_t)(t0g+trow+n)*32 + bhi)*128         \
                                   + 16*quad;                                    \
        v4i a0 = *(const v4i*)kp;          /* A-operand direct from global */    \
        v4i a1 = *(const v4i*)(kp + 64);                                         \
        float ksr[4], kmr[4], skr[4];                                            \
        int tgb = t0g + trow + 4*quad;                                           \
        _Pragma("unroll")                                                        \
        for (int r = 0; r < 4; ++r) {                                            \
            int tl = trow + 4*quad + r;                                          \
            ksr[r] = ktA[tl]; kmr[r] = ktB[tl]; skr[r] = ktC[tl];                \
        }                                                                        \
        _Pragma("unroll")                                                        \
        for (int cb = 0; cb < 4; ++cb) {                                         \
            v4i qb0 = *(const v4i*)(q8s + (16*cb + n)*144 + 16*quad);            \
            v4i qb1 = *(const v4i*)(q8s + (16*cb + n)*144 + 64 + 16*quad);       \
            v4i acc = MFMA16(a0, qb0, vzero);                                    \
            acc = MFMA16(a1, qb1, acc);                                          \
            int cby[4];                                                          \
            _Pragma("unroll")                                                    \
            for (int r = 0; r < 4; ++r) {                                        \
                float Sf = (float)acc[r];                                        \
                float x = fmaf(ksr[r], fmaf(qc1[cb], Sf, qc2[cb]*skr[r]),        \
                               fmaf(kmr[r], qc3[cb], qmxn[cb]));                 \
                if (MASKED) x = (tgb + r > qgq[cb]) ? -INFINITY : x;             \
                float e = EXP2F(x);                                              \
                float f = fmaf(e, qu1[cb], qw1[cb]) + 8388608.0f; /* RNE int */  \
                cby[r] = __float_as_int(f);                                      \
            }                                                                    \
            unsigned t01 = __builtin_amdgcn_perm((unsigned)cby[1],               \
                                                 (unsigned)cby[0], 0x00000400u); \
            unsigned t23 = __builtin_amdgcn_perm((unsigned)cby[3],               \
                                                 (unsigned)cby[2], 0x04000000u); \
            int packed = (int)(__builtin_amdgcn_perm(t23, t01, 0x07060100u)      \
                               ^ 0x80808080u);  /* code - 128 per byte */        \
            *(int*)(pcs + (16*cb + n)*144 + trow + 4*quad) = packed;             \
        }                                                                        \
    }                                                                            \
    __syncthreads();                                                             \
    {                                                                            \
        v4i a0 = *(const v4i*)(pcs + (16*w + n)*144 + 16*quad);                  \
        v4i a1 = *(const v4i*)(pcs + (16*w + n)*144 + 64 + 16*quad);             \
        v4i c1a = MFMA16(a0, ones, vzero);                                       \
        c1a = MFMA16(a1, ones, c1a);                                             \
        float c1f[4];                                                            \
        _Pragma("unroll")                                                        \
        for (int r = 0; r < 4; ++r) c1f[r] = (float)c1a[r];                      \
        _Pragma("unroll")                                                        \
        for (int db = 0; db < 8; ++db) {                                         \
            v4i b0 = *(const v4i*)(v8s + (16*db + n)*144 + 16*quad);             \
            v4i b1 = *(const v4i*)(v8s + (16*db + n)*144 + 64 + 16*quad);        \
            v4i cv = MFMA16(a0, b0, vzero);                                      \
            cv = MFMA16(a1, b1, cv);                                             \
            int d = 16*db + n;                                                   \
            float vs = vsA[d], vm = vsB[d];                                      \
            _Pragma("unroll")                                                    \
            for (int r = 0; r < 4; ++r)                                          \
                outa[r][db] = fmaf(vs, (float)cv[r],                             \
                                   fmaf(vm, c1f[r], outa[r][db]));               \
        }                                                                        \
    }                                                                            \
  } while (0)

    {
        int kt;
        for (kt = 0; kt < kt_end; ++kt) P2_TILE(false);
        kt = kt_end;
        if (causal) P2_TILE(true); else P2_TILE(false);
    }

    // ---- epilogue: out = psc*(outa + cgs) + pmin*vsum ----
    float pscr[4], pmnr[4];
    #pragma unroll
    for (int r = 0; r < 4; ++r) {
        int qq = 16*w + 4*quad + r;
        pscr[r] = rs_psc[qq]; pmnr[r] = rs_pmn[qq];
    }
    #pragma unroll
    for (int db = 0; db < 8; ++db) {
        int d = 16*db + n;
        float vsum = vsumL[d];
        float cgs  = cgsL[d];
        #pragma unroll
        for (int r = 0; r < 4; ++r) {
            int s = s0 + 16*w + 4*quad + r;
            OUT[(size_t)s*RSTR + boff + d] = fmaf(pscr[r], outa[r][db] + cgs, pmnr[r]*vsum);
        }
    }
}

extern "C" void kernel_launch(void* const* d_in, const int* in_sizes, int n_in,
                              void* d_out, int out_size, void* d_ws, size_t ws_size,
                              hipStream_t stream) {
    (void)in_sizes; (void)n_in; (void)out_size; (void)ws_size;
    const float* Q   = (const float*)d_in[0];
    const float* K   = (const float*)d_in[1];
    const float* V   = (const float*)d_in[2];
    const float* QMN = (const float*)d_in[3];
    const float* QSC = (const float*)d_in[4];
    const float* KMN = (const float*)d_in[5];
    const float* KSC = (const float*)d_in[6];
    const float* VMN = (const float*)d_in[7];
    const float* VSC = (const float*)d_in[8];
    const int*   CS  = (const int*)d_in[9];
    float* out = (float*)d_out;

    char* ws = (char*)d_ws;
    signed char* K8  = (signed char*)(ws + WS_K8);
    signed char* V8T = (signed char*)(ws + WS_V8T);
    float* SKs  = (float*)(ws + WS_SK);
    float* GSVp = (float*)(ws + WS_GSV);
    float* STmx = (float*)(ws + WS_STMX);
    float* STdn = (float*)(ws + WS_STDN);
    float* STmn = (float*)(ws + WS_STMN);

    prep_k<<<1024, 256, 0, stream>>>(K, K8, SKs);
    prep_v<<<512, 256, 0, stream>>>(V, V8T, GSVp);
    attn_p1<<<1024, 256, 0, stream>>>(Q, K8, QMN, QSC, KMN, KSC, SKs, CS,
                                      STmx, STdn, STmn);
    attn_p2<<<1024, 256, 0, stream>>>(Q, K8, V8T, QMN, QSC, KMN, KSC, VMN, VSC,
                                      SKs, GSVp, STmx, STdn, STmn, CS, out);
}

// Round 7
// 244.803 us; speedup vs baseline: 1.0513x; 1.0513x over previous
//
#include <hip/hip_runtime.h>
#include <math.h>

// Quantized causal attention on int8 MFMA — R13.
// R12 post-mortem: phase-split refuted (p1 spilled to scratch at (256,4):
// VGPR 64, occ 3%, 148us; p1+p2=225 >= 120). Reverted to R11 per tripwire.
// Register wall confirmed 4x: monolith runs at 2 blocks/CU, full stop.
// R13 = R11 + exposed-latency cuts that don't touch register structure:
//  1. P1 k8s double-buffered, ONE barrier/tile (was 2): issue next-tile
//     global loads at tile top -> compute current -> write other buffer ->
//     barrier. Free LDS-wise: k8s-dbuf (36.9KB, P1-only) aliases v8s+pcs
//     (27.6KB, P2-only) in one union; total LDS 61.4 -> 52.5KB.
//  2. fmin min-tracking only where pmin is consumed (qt==31 or non-causal),
//     via compile-time loop split (saves 32 fmin/tile in 31/32 blocks).
//  3. prep_k+prep_v fused to one launch (V-heavy blocks first).
// Tripwires: WRITE_SIZE ~32.8MB (spill), attn >= 120us refutes 1-barrier P1.

#define S_LEN 2048
#define BATCH 2
#define NH    16
#define HD    128
#define RSTR  4096   // floats between seq positions
#define SCALE2 (0.08838834764831845f * 1.4426950408889634f)   // (1/sqrt(128))/ln2
#define EXP2F(x) __builtin_amdgcn_exp2f(x)

typedef int v4i __attribute__((ext_vector_type(4)));
#define MFMA16(a,b,c) __builtin_amdgcn_mfma_i32_16x16x64_i8((a),(b),(c),0,0,0)

// ws byte offsets
#define WS_K8   0u
#define WS_V8T  (8u*1024u*1024u)
#define WS_SK   (16u*1024u*1024u)
#define WS_GSV  (WS_SK + 256u*1024u)

__device__ __forceinline__ int sbsum(unsigned p) {
    return (int)(signed char)(p) + (int)(signed char)(p>>8)
         + (int)(signed char)(p>>16) + (int)(signed char)(p>>24);
}

// ---- fused prep: V transpose+GSV (blocks 0..511, heavy, first) ----
// ----             K pack+SKs       (blocks 512..1535)             ----
__global__ __launch_bounds__(256) void prep(
    const float* __restrict__ K, const float* __restrict__ V,
    signed char* __restrict__ K8, float* __restrict__ SKs,
    signed char* __restrict__ V8T, float* __restrict__ GSV)
{
    __shared__ int v8i[128*33];
    const int tid = threadIdx.x;
    const int bx  = blockIdx.x;
    if (bx >= 512) {
        const int base = (bx - 512)*2048 + tid;       // 1024 blocks x 256 x 8
        #pragma unroll
        for (int rep = 0; rep < 8; ++rep) {
            int idx = base + rep*256;                 // float4 index
            float4 x = *(const float4*)(K + (size_t)idx*4);
            int a=(int)x.x, b=(int)x.y, c=(int)x.z, d=(int)x.w;
            ((int*)K8)[idx] = (a&255)|((b&255)<<8)|((c&255)<<16)|((d&255)<<24);
            float s = x.x + x.y + x.z + x.w;
            #pragma unroll
            for (int off = 16; off >= 1; off >>= 1) s += __shfl_xor(s, off);
            if ((tid & 31) == 0) SKs[idx >> 5] = s;
        }
    } else {
        const int bid = bx;
        const int bh = bid & 31, ck = bid >> 5;   // ck = 128-t chunk = v-group
        const int b = bh >> 4, h = bh & 15;
        const int t0 = ck * 128;
        const int boff = b*2048 + h*128;
        #pragma unroll
        for (int it = 0; it < 16; ++it) {
            int idx = tid + it*256;
            int t = idx >> 5, dw = idx & 31;
            float4 x = *(const float4*)(V + (size_t)(t0+t)*RSTR + boff + 4*dw);
            int a=(int)x.x, b2=(int)x.y, c=(int)x.z, d=(int)x.w;
            v8i[t*33 + dw] = (a&255)|((b2&255)<<8)|((c&255)<<16)|((d&255)<<24);
        }
        __syncthreads();
        #pragma unroll
        for (int it = 0; it < 4; ++it) {
            int j = tid + it*256;
            int tg = j & 31, dw = j >> 5;
            unsigned r0 = (unsigned)v8i[(4*tg+0)*33 + dw];
            unsigned r1 = (unsigned)v8i[(4*tg+1)*33 + dw];
            unsigned r2 = (unsigned)v8i[(4*tg+2)*33 + dw];
            unsigned r3 = (unsigned)v8i[(4*tg+3)*33 + dw];
            unsigned x01 = __builtin_amdgcn_perm(r1, r0, 0x05010400u);
            unsigned x23 = __builtin_amdgcn_perm(r3, r2, 0x05010400u);
            unsigned y01 = __builtin_amdgcn_perm(r1, r0, 0x07030602u);
            unsigned y23 = __builtin_amdgcn_perm(r3, r2, 0x07030602u);
            unsigned p[4];
            p[0] = __builtin_amdgcn_perm(x23, x01, 0x05040100u);
            p[1] = __builtin_amdgcn_perm(x23, x01, 0x07060302u);
            p[2] = __builtin_amdgcn_perm(y23, y01, 0x05040100u);
            p[3] = __builtin_amdgcn_perm(y23, y01, 0x07060302u);
            int s[4];
            #pragma unroll
            for (int jj = 0; jj < 4; ++jj) {
                int d = 4*dw + jj;
                *(int*)(V8T + ((size_t)bh*128 + d)*2048 + t0 + 4*tg) = (int)p[jj];
                s[jj] = sbsum(p[jj]);
            }
            #pragma unroll
            for (int off = 1; off < 32; off <<= 1) {
                #pragma unroll
                for (int jj = 0; jj < 4; ++jj) s[jj] += __shfl_xor(s[jj], off);
            }
            if (tg == 0) {
                #pragma unroll
                for (int jj = 0; jj < 4; ++jj)
                    GSV[((size_t)bh*16 + ck)*128 + 4*dw + jj] = (float)s[jj];
            }
        }
    }
}

// ---- main kernel ----
__global__ __launch_bounds__(256, 2) void attn_main(
    const float* __restrict__ Q,
    const signed char* __restrict__ K8, const signed char* __restrict__ V8T,
    const float* __restrict__ QMN, const float* __restrict__ QSC,
    const float* __restrict__ KMN, const float* __restrict__ KSC,
    const float* __restrict__ VMN, const float* __restrict__ VSC,
    const float* __restrict__ SKs, const float* __restrict__ GSV,
    const int* __restrict__ CAUSAL, float* __restrict__ OUT)
{
    __shared__ __align__(16) signed char q8s[64*144];     // [q][d] int8
    __shared__ __align__(16) signed char un[2*128*144];   // P1: k8s dbuf | P2: v8s|pcs
    __shared__ float rs_c1[64], rs_c2[64], rs_c3[64];
    __shared__ float rs_mx[64], rs_den[64], rs_mn[64];
    __shared__ float rs_u1[64], rs_w1[64], rs_psc[64], rs_pmn[64];
    __shared__ float ktA[2][128], ktB[2][128], ktC[2][128];
    __shared__ float vsA[128], vsB[128];                  // vs, vm (current group)
    __shared__ float vsumL[128], cgsL[128];               // VSUM / CGS row

    signed char* v8s = un;              // Phase-2 alias (V [d][t])
    signed char* pcs = un + 128*144;    // Phase-2 alias (codes [q][t])

    const int tid  = threadIdx.x;
    const int w    = tid >> 6;
    const int lane = tid & 63;
    const int n    = lane & 15;
    const int quad = lane >> 4;
    const int bhi  = blockIdx.x & 31;
    const int qt   = 31 - (int)(blockIdx.x >> 5);   // heavy tiles first
    const int b    = bhi >> 4, h = bhi & 15;
    const int causal = *CAUSAL;
    const int s0   = qt * 64;
    const int boff = b*2048 + h*128;
    const v4i vzero = {0,0,0,0};
    const v4i ones  = {0x01010101,0x01010101,0x01010101,0x01010101};

    const int kt_end = causal ? ((s0 + 63) >> 7) : 15;

    // ---- stage Q tile + K tile 0 (buf 0) + consts ----
    #pragma unroll
    for (int it = 0; it < 8; ++it) {
        int idx = tid + it*256;
        int row = idx >> 5, d4 = (idx & 31) << 2;
        float4 x = *(const float4*)(Q + (size_t)(s0+row)*RSTR + boff + d4);
        int a=(int)x.x, b2=(int)x.y, c=(int)x.z, d=(int)x.w;
        *(int*)(q8s + row*144 + d4) = (a&255)|((b2&255)<<8)|((c&255)<<16)|((d&255)<<24);
    }
    #pragma unroll
    for (int it = 0; it < 4; ++it) {
        int idx = tid + it*256;
        int trow = idx >> 3, doff = (idx & 7) << 4;
        *(uint4*)(un + trow*144 + doff) =
            *(const uint4*)(K8 + ((size_t)trow*32 + bhi)*128 + doff);
    }
    if (tid < 64) {
        int si = (s0 + tid)*32 + bhi;
        rs_c1[tid] = QSC[si]; rs_c2[tid] = QMN[si];
    } else if (tid >= 128) {
        int d = tid - 128;
        int si = d*32 + bhi;
        ktA[0][d] = KSC[si]*SCALE2; ktB[0][d] = KMN[si]*SCALE2; ktC[0][d] = SKs[si];
    }
    __syncthreads();

    v4i a0p = *(const v4i*)(q8s + (16*w + n)*144 + 16*quad);
    v4i a1p = *(const v4i*)(q8s + (16*w + n)*144 + 64 + 16*quad);

    // Q token sums via one MFMA-ones pair -> rs_c3 (prep never reads Q)
    {
        v4i qsum = MFMA16(a0p, ones, vzero);
        qsum = MFMA16(a1p, ones, qsum);
        if (n == 0) {
            #pragma unroll
            for (int r = 0; r < 4; ++r) {
                int qq = 16*w + 4*quad + r;
                rs_c3[qq] = fmaf(rs_c1[qq], (float)qsum[r], 128.0f*rs_c2[qq]);
            }
        }
    }
    __syncthreads();

    float c1r[4], c2r[4], c3r[4]; int qgr[4];
    #pragma unroll
    for (int r = 0; r < 4; ++r) {
        int qq = 16*w + 4*quad + r;
        c1r[r] = rs_c1[qq]; c2r[r] = rs_c2[qq]; c3r[r] = rs_c3[qq];
        qgr[r] = s0 + qq;
    }

    float m[4], l[4], mn[4];
    #pragma unroll
    for (int r = 0; r < 4; ++r) { m[r] = -INFINITY; l[r] = 0.f; mn[r] = INFINITY; }

    // ================= Phase 1: softmax stats, 1 barrier/tile =================
    // dbuf: issue next-tile loads at top, compute current, write other buffer,
    // single barrier. DOMN compile-time-splits the fmin tracking.
#define P1_TILE(MASKED, DOMN)                                                    \
  do {                                                                           \
    const int t0g = kt * 128;                                                    \
    const int cur = kt & 1;                                                      \
    const signed char* k8c = un + cur*(128*144);                                 \
    signed char* k8n = un + (cur^1)*(128*144);                                   \
    const bool hn = kt < kt_end;                                                 \
    uint4 nx[4]; float nA = 0.f, nB = 0.f, nC = 0.f;                             \
    if (hn) {                                                                    \
        _Pragma("unroll")                                                        \
        for (int it = 0; it < 4; ++it) {                                         \
            int idx = tid + it*256;                                              \
            int trow = idx >> 3, doff = (idx & 7) << 4;                          \
            nx[it] = *(const uint4*)(K8 +                                        \
                      ((size_t)(t0g + 128 + trow)*32 + bhi)*128 + doff);         \
        }                                                                        \
        if (tid < 128) {                                                         \
            int si = (t0g + 128 + tid)*32 + bhi;                                 \
            nA = KSC[si]*SCALE2; nB = KMN[si]*SCALE2; nC = SKs[si];              \
        }                                                                        \
    }                                                                            \
    float tmax[4], sarr[8][4];                                                   \
    _Pragma("unroll")                                                            \
    for (int r = 0; r < 4; ++r) tmax[r] = -INFINITY;                             \
    _Pragma("unroll")                                                            \
    for (int tb = 0; tb < 8; ++tb) {                                             \
        v4i b0 = *(const v4i*)(k8c + (16*tb + n)*144 + 16*quad);                 \
        v4i b1 = *(const v4i*)(k8c + (16*tb + n)*144 + 64 + 16*quad);            \
        v4i acc = MFMA16(a0p, b0, vzero);                                        \
        acc = MFMA16(a1p, b1, acc);                                              \
        int tl = 16*tb + n;                                                      \
        float kA = ktA[cur][tl], kB = ktB[cur][tl], kC = ktC[cur][tl];           \
        _Pragma("unroll")                                                        \
        for (int r = 0; r < 4; ++r) {                                            \
            float Sf = (float)acc[r];                                            \
            float sv = fmaf(kA, fmaf(c1r[r], Sf, c2r[r]*kC), kB*c3r[r]);         \
            if (MASKED) sv = (t0g + tl > qgr[r]) ? -INFINITY : sv;               \
            sarr[tb][r] = sv;                                                    \
            tmax[r] = fmaxf(tmax[r], sv);                                        \
            if (DOMN) mn[r] = fminf(mn[r], sv);                                  \
        }                                                                        \
    }                                                                            \
    _Pragma("unroll")                                                            \
    for (int r = 0; r < 4; ++r) {                                                \
        float mm = fmaxf(m[r], tmax[r]);                                         \
        if (mm > -INFINITY) {                                                    \
            float e0 = EXP2F(sarr[0][r]-mm) + EXP2F(sarr[1][r]-mm);              \
            float e1 = EXP2F(sarr[2][r]-mm) + EXP2F(sarr[3][r]-mm);              \
            float e2 = EXP2F(sarr[4][r]-mm) + EXP2F(sarr[5][r]-mm);              \
            float e3 = EXP2F(sarr[6][r]-mm) + EXP2F(sarr[7][r]-mm);              \
            l[r] = fmaf(l[r], EXP2F(m[r]-mm), (e0+e1)+(e2+e3));                  \
            m[r] = mm;                                                           \
        }                                                                        \
    }                                                                            \
    if (hn) {                                                                    \
        _Pragma("unroll")                                                        \
        for (int it = 0; it < 4; ++it) {                                         \
            int idx = tid + it*256;                                              \
            int trow = idx >> 3, doff = (idx & 7) << 4;                          \
            *(uint4*)(k8n + trow*144 + doff) = nx[it];                           \
        }                                                                        \
        if (tid < 128) {                                                         \
            ktA[cur^1][tid] = nA; ktB[cur^1][tid] = nB; ktC[cur^1][tid] = nC;    \
        }                                                                        \
    }                                                                            \
    __syncthreads();                                                             \
  } while (0)

    if ((!causal) || (qt == 31)) {
        int kt;
        for (kt = 0; kt < kt_end; ++kt) P1_TILE(false, true);
        kt = kt_end;
        if (causal) P1_TILE(true, true); else P1_TILE(false, true);
    } else {
        int kt;
        for (kt = 0; kt < kt_end; ++kt) P1_TILE(false, false);
        kt = kt_end;
        P1_TILE(true, false);
    }

    // reduce stats across the 16 col-lanes
    #pragma unroll
    for (int r = 0; r < 4; ++r) {
        #pragma unroll
        for (int off = 1; off < 16; off <<= 1) {
            float m2 = __shfl_xor(m[r], off);
            float l2 = __shfl_xor(l[r], off);
            float n2 = __shfl_xor(mn[r], off);
            float mm = fmaxf(m[r], m2);
            if (mm > -INFINITY) l[r] = l[r]*EXP2F(m[r]-mm) + l2*EXP2F(m2-mm);
            m[r] = mm;
            mn[r] = fminf(mn[r], n2);
        }
        if (n == 0) {
            int qq = 16*w + 4*quad + r;
            rs_mx[qq] = m[r]; rs_den[qq] = l[r]; rs_mn[qq] = mn[r];
        }
    }
    __syncthreads();   // all P1 reads of un done before P2 overwrites
    if (tid < 64) {
        float mx = rs_mx[tid], den = rs_den[tid], mnv = rs_mn[tid];
        float invd = 1.0f/den;
        int s = s0 + tid;
        bool hasmask = (causal != 0) && (s < S_LEN-1);
        float pmin = hasmask ? 0.0f : EXP2F(mnv - mx)*invd;
        float psc  = (invd - pmin)/255.0f + 1e-12f;
        float ipsc = 1.0f/psc;
        rs_u1[tid] = invd*ipsc; rs_w1[tid] = -pmin*ipsc;
        rs_psc[tid] = psc; rs_pmn[tid] = pmin;
    } else if (tid >= 128) {
        // in-block VSUM (full row) + CGS (cumulative to kt_end) for this bh
        int d = tid - 128;
        float vsum = 0.f, cgs = 0.f;
        #pragma unroll
        for (int g = 0; g < 16; ++g) {
            float gs = GSV[((size_t)bhi*16 + g)*128 + d];
            int vi = ((g*BATCH + b)*NH + h)*HD + d;
            float vs = VSC[vi], vm = VMN[vi];
            vsum = fmaf(vs, gs, fmaf(128.0f, vm, vsum));
            if (g <= kt_end) cgs = fmaf(128.0f*vs, gs, fmaf(16384.0f, vm, cgs));
        }
        vsumL[d] = vsum; cgsL[d] = cgs;
    }
    __syncthreads();

    // ---- hoist P2 tile-invariants: Q B-fragments + per-q constants ----
    v4i qb0[4], qb1[4];
    float qc1[4], qc2[4], qc3[4], qmxn[4], qu1[4], qw1[4];
    int qgq[4];
    #pragma unroll
    for (int cb = 0; cb < 4; ++cb) {
        int qcol = 16*cb + n;
        qb0[cb] = *(const v4i*)(q8s + qcol*144 + 16*quad);
        qb1[cb] = *(const v4i*)(q8s + qcol*144 + 64 + 16*quad);
        qc1[cb] = rs_c1[qcol]; qc2[cb] = rs_c2[qcol]; qc3[cb] = rs_c3[qcol];
        qmxn[cb] = -rs_mx[qcol]; qu1[cb] = rs_u1[qcol]; qw1[cb] = rs_w1[qcol];
        qgq[cb] = s0 + qcol;
    }

    // ================= Phase 2: requant + PV (R0/R11 3-barrier form) =========
    float outa[4][8];
    #pragma unroll
    for (int r = 0; r < 4; ++r)
        #pragma unroll
        for (int db = 0; db < 8; ++db) outa[r][db] = 0.f;

#define P2_TILE(MASKED)                                                          \
  do {                                                                           \
    const int t0g = kt * 128;                                                    \
    __syncthreads();   /* previous PV reads of v8s/pcs done */                   \
    _Pragma("unroll")                                                            \
    for (int it = 0; it < 4; ++it) {                                             \
        int idx = tid + it*256;                                                  \
        int trow = idx >> 3, doff = (idx & 7) << 4;                              \
        *(uint4*)(v8s + trow*144 + doff) =                                       \
            *(const uint4*)(V8T + ((size_t)bhi*128 + trow)*2048 + t0g + doff);   \
    }                                                                            \
    if (tid < 128) {                                                             \
        int si = (t0g + tid)*32 + bhi;                                           \
        ktA[0][tid] = KSC[si]*SCALE2; ktB[0][tid] = KMN[si]*SCALE2;              \
        ktC[0][tid] = SKs[si];                                                   \
    } else {                                                                     \
        int d = tid - 128;                                                       \
        int vi = ((kt*BATCH + b)*NH + h)*HD + d;                                 \
        vsA[d] = VSC[vi]; vsB[d] = VMN[vi];                                      \
    }                                                                            \
    __syncthreads();                                                             \
    _Pragma("unroll")                                                            \
    for (int rb = 0; rb < 2; ++rb) {                                             \
        int trow = 32*w + 16*rb;                                                 \
        const signed char* kp = K8 + ((size_t)(t0g+trow+n)*32 + bhi)*128         \
                                   + 16*quad;                                    \
        v4i a0 = *(const v4i*)kp;          /* A-operand direct from global */    \
        v4i a1 = *(const v4i*)(kp + 64);                                         \
        float ksr[4], kmr[4], skr[4];                                            \
        int tgb = t0g + trow + 4*quad;                                           \
        _Pragma("unroll")                                                        \
        for (int r = 0; r < 4; ++r) {                                            \
            int tl = trow + 4*quad + r;                                          \
            ksr[r] = ktA[0][tl]; kmr[r] = ktB[0][tl]; skr[r] = ktC[0][tl];       \
        }                                                                        \
        _Pragma("unroll")                                                        \
        for (int cb = 0; cb < 4; ++cb) {                                         \
            v4i acc = MFMA16(a0, qb0[cb], vzero);                                \
            acc = MFMA16(a1, qb1[cb], acc);                                      \
            int cby[4];                                                          \
            _Pragma("unroll")                                                    \
            for (int r = 0; r < 4; ++r) {                                        \
                float Sf = (float)acc[r];                                        \
                float x = fmaf(ksr[r], fmaf(qc1[cb], Sf, qc2[cb]*skr[r]),        \
                               fmaf(kmr[r], qc3[cb], qmxn[cb]));                 \
                if (MASKED) x = (tgb + r > qgq[cb]) ? -INFINITY : x;             \
                float e = EXP2F(x);                                              \
                float f = fmaf(e, qu1[cb], qw1[cb]) + 8388608.0f; /* RNE int */  \
                cby[r] = __float_as_int(f);                                      \
            }                                                                    \
            unsigned t01 = __builtin_amdgcn_perm((unsigned)cby[1],               \
                                                 (unsigned)cby[0], 0x00000400u); \
            unsigned t23 = __builtin_amdgcn_perm((unsigned)cby[3],               \
                                                 (unsigned)cby[2], 0x04000000u); \
            int packed = (int)(__builtin_amdgcn_perm(t23, t01, 0x07060100u)      \
                               ^ 0x80808080u);  /* code - 128 per byte */        \
            *(int*)(pcs + (16*cb + n)*144 + trow + 4*quad) = packed;             \
        }                                                                        \
    }                                                                            \
    __syncthreads();                                                             \
    {                                                                            \
        v4i a0 = *(const v4i*)(pcs + (16*w + n)*144 + 16*quad);                  \
        v4i a1 = *(const v4i*)(pcs + (16*w + n)*144 + 64 + 16*quad);             \
        v4i c1a = MFMA16(a0, ones, vzero);                                       \
        c1a = MFMA16(a1, ones, c1a);                                             \
        float c1f[4];                                                            \
        _Pragma("unroll")                                                        \
        for (int r = 0; r < 4; ++r) c1f[r] = (float)c1a[r];                      \
        _Pragma("unroll")                                                        \
        for (int db = 0; db < 8; ++db) {                                         \
            v4i b0 = *(const v4i*)(v8s + (16*db + n)*144 + 16*quad);             \
            v4i b1 = *(const v4i*)(v8s + (16*db + n)*144 + 64 + 16*quad);        \
            v4i cv = MFMA16(a0, b0, vzero);                                      \
            cv = MFMA16(a1, b1, cv);                                             \
            int d = 16*db + n;                                                   \
            float vs = vsA[d], vm = vsB[d];                                      \
            _Pragma("unroll")                                                    \
            for (int r = 0; r < 4; ++r)                                          \
                outa[r][db] = fmaf(vs, (float)cv[r],                             \
                                   fmaf(vm, c1f[r], outa[r][db]));               \
        }                                                                        \
    }                                                                            \
  } while (0)

    {
        int kt;
        for (kt = 0; kt < kt_end; ++kt) P2_TILE(false);
        kt = kt_end;
        if (causal) P2_TILE(true); else P2_TILE(false);
    }

    // ---- epilogue: out = psc*(outa + cgs) + pmin*vsum ----
    float pscr[4], pmnr[4];
    #pragma unroll
    for (int r = 0; r < 4; ++r) {
        int qq = 16*w + 4*quad + r;
        pscr[r] = rs_psc[qq]; pmnr[r] = rs_pmn[qq];
    }
    #pragma unroll
    for (int db = 0; db < 8; ++db) {
        int d = 16*db + n;
        float vsum = vsumL[d];
        float cgs  = cgsL[d];
        #pragma unroll
        for (int r = 0; r < 4; ++r) {
            int s = s0 + 16*w + 4*quad + r;
            OUT[(size_t)s*RSTR + boff + d] = fmaf(pscr[r], outa[r][db] + cgs, pmnr[r]*vsum);
        }
    }
}

extern "C" void kernel_launch(void* const* d_in, const int* in_sizes, int n_in,
                              void* d_out, int out_size, void* d_ws, size_t ws_size,
                              hipStream_t stream) {
    (void)in_sizes; (void)n_in; (void)out_size; (void)ws_size;
    const float* Q   = (const float*)d_in[0];
    const float* K   = (const float*)d_in[1];
    const float* V   = (const float*)d_in[2];
    const float* QMN = (const float*)d_in[3];
    const float* QSC = (const float*)d_in[4];
    const float* KMN = (const float*)d_in[5];
    const float* KSC = (const float*)d_in[6];
    const float* VMN = (const float*)d_in[7];
    const float* VSC = (const float*)d_in[8];
    const int*   CS  = (const int*)d_in[9];
    float* out = (float*)d_out;

    char* ws = (char*)d_ws;
    signed char* K8  = (signed char*)(ws + WS_K8);
    signed char* V8T = (signed char*)(ws + WS_V8T);
    float* SKs  = (float*)(ws + WS_SK);
    float* GSVp = (float*)(ws + WS_GSV);

    prep<<<1536, 256, 0, stream>>>(K, V, K8, SKs, V8T, GSVp);
    attn_main<<<1024, 256, 0, stream>>>(Q, K8, V8T, QMN, QSC, KMN, KSC, VMN, VSC,
                                        SKs, GSVp, CS, out);
}

// Round 8
// 238.514 us; speedup vs baseline: 1.0790x; 1.0264x over previous
//
#include <hip/hip_runtime.h>
#include <math.h>

// Quantized causal attention on int8 MFMA — R14 (consolidation).
// R13 post-mortem: 1-barrier dbuf P1 refuted (attn 144.8us; same VALU/MFMA
// busy-time as R11 -> +25us pure stall from register-held prefetch; implicit
// 2-block wave overlap already hides R11's staging). But fused prep WORKED:
// gap 123 -> 100us. R14 = the two measured bests, nothing speculative:
//  1. attn_main = R11 verbatim (120us proven): separate k8s/v8s, 2-barrier
//     P1, 3-barrier P2, hoisted qb0/qb1, qsum-MFMA rs_c3, (256,2).
//     + ONE neutral addition: compile-time DOMN split (fmin tracked only in
//     blocks that consume pmin: non-causal or qt==31; R13-validated macro).
//  2. prep = R13's fused single launch (V-heavy blocks first) verbatim.
// Tripwires: attn > 122us -> DOMN perturbed regalloc, revert; gap > 110us ->
// fused-prep gain was noise. Next lever if this lands: T2 XOR-swizzle on
// k8s/v8s/pcs (5.45M LDS conflict cycles ~ 7% of attn time).

#define S_LEN 2048
#define BATCH 2
#define NH    16
#define HD    128
#define RSTR  4096   // floats between seq positions
#define SCALE2 (0.08838834764831845f * 1.4426950408889634f)   // (1/sqrt(128))/ln2
#define EXP2F(x) __builtin_amdgcn_exp2f(x)

typedef int v4i __attribute__((ext_vector_type(4)));
#define MFMA16(a,b,c) __builtin_amdgcn_mfma_i32_16x16x64_i8((a),(b),(c),0,0,0)

// ws byte offsets
#define WS_K8   0u
#define WS_V8T  (8u*1024u*1024u)
#define WS_SK   (16u*1024u*1024u)
#define WS_GSV  (WS_SK + 256u*1024u)

__device__ __forceinline__ int sbsum(unsigned p) {
    return (int)(signed char)(p) + (int)(signed char)(p>>8)
         + (int)(signed char)(p>>16) + (int)(signed char)(p>>24);
}

// ---- fused prep: V transpose+GSV (blocks 0..511, heavy, first) ----
// ----             K pack+SKs       (blocks 512..1535)             ----
__global__ __launch_bounds__(256) void prep(
    const float* __restrict__ K, const float* __restrict__ V,
    signed char* __restrict__ K8, float* __restrict__ SKs,
    signed char* __restrict__ V8T, float* __restrict__ GSV)
{
    __shared__ int v8i[128*33];
    const int tid = threadIdx.x;
    const int bx  = blockIdx.x;
    if (bx >= 512) {
        const int base = (bx - 512)*2048 + tid;       // 1024 blocks x 256 x 8
        #pragma unroll
        for (int rep = 0; rep < 8; ++rep) {
            int idx = base + rep*256;                 // float4 index
            float4 x = *(const float4*)(K + (size_t)idx*4);
            int a=(int)x.x, b=(int)x.y, c=(int)x.z, d=(int)x.w;
            ((int*)K8)[idx] = (a&255)|((b&255)<<8)|((c&255)<<16)|((d&255)<<24);
            float s = x.x + x.y + x.z + x.w;
            #pragma unroll
            for (int off = 16; off >= 1; off >>= 1) s += __shfl_xor(s, off);
            if ((tid & 31) == 0) SKs[idx >> 5] = s;
        }
    } else {
        const int bid = bx;
        const int bh = bid & 31, ck = bid >> 5;   // ck = 128-t chunk = v-group
        const int b = bh >> 4, h = bh & 15;
        const int t0 = ck * 128;
        const int boff = b*2048 + h*128;
        #pragma unroll
        for (int it = 0; it < 16; ++it) {
            int idx = tid + it*256;
            int t = idx >> 5, dw = idx & 31;
            float4 x = *(const float4*)(V + (size_t)(t0+t)*RSTR + boff + 4*dw);
            int a=(int)x.x, b2=(int)x.y, c=(int)x.z, d=(int)x.w;
            v8i[t*33 + dw] = (a&255)|((b2&255)<<8)|((c&255)<<16)|((d&255)<<24);
        }
        __syncthreads();
        #pragma unroll
        for (int it = 0; it < 4; ++it) {
            int j = tid + it*256;
            int tg = j & 31, dw = j >> 5;
            unsigned r0 = (unsigned)v8i[(4*tg+0)*33 + dw];
            unsigned r1 = (unsigned)v8i[(4*tg+1)*33 + dw];
            unsigned r2 = (unsigned)v8i[(4*tg+2)*33 + dw];
            unsigned r3 = (unsigned)v8i[(4*tg+3)*33 + dw];
            unsigned x01 = __builtin_amdgcn_perm(r1, r0, 0x05010400u);
            unsigned x23 = __builtin_amdgcn_perm(r3, r2, 0x05010400u);
            unsigned y01 = __builtin_amdgcn_perm(r1, r0, 0x07030602u);
            unsigned y23 = __builtin_amdgcn_perm(r3, r2, 0x07030602u);
            unsigned p[4];
            p[0] = __builtin_amdgcn_perm(x23, x01, 0x05040100u);
            p[1] = __builtin_amdgcn_perm(x23, x01, 0x07060302u);
            p[2] = __builtin_amdgcn_perm(y23, y01, 0x05040100u);
            p[3] = __builtin_amdgcn_perm(y23, y01, 0x07060302u);
            int s[4];
            #pragma unroll
            for (int jj = 0; jj < 4; ++jj) {
                int d = 4*dw + jj;
                *(int*)(V8T + ((size_t)bh*128 + d)*2048 + t0 + 4*tg) = (int)p[jj];
                s[jj] = sbsum(p[jj]);
            }
            #pragma unroll
            for (int off = 1; off < 32; off <<= 1) {
                #pragma unroll
                for (int jj = 0; jj < 4; ++jj) s[jj] += __shfl_xor(s[jj], off);
            }
            if (tg == 0) {
                #pragma unroll
                for (int jj = 0; jj < 4; ++jj)
                    GSV[((size_t)bh*16 + ck)*128 + 4*dw + jj] = (float)s[jj];
            }
        }
    }
}

// ---- main kernel (R11 structure, verbatim + DOMN split) ----
__global__ __launch_bounds__(256, 2) void attn_main(
    const float* __restrict__ Q,
    const signed char* __restrict__ K8, const signed char* __restrict__ V8T,
    const float* __restrict__ QMN, const float* __restrict__ QSC,
    const float* __restrict__ KMN, const float* __restrict__ KSC,
    const float* __restrict__ VMN, const float* __restrict__ VSC,
    const float* __restrict__ SKs, const float* __restrict__ GSV,
    const int* __restrict__ CAUSAL, float* __restrict__ OUT)
{
    __shared__ __align__(16) signed char q8s[64*144];   // [q][d] int8
    __shared__ __align__(16) signed char k8s[128*144];  // [t][d] int8 (phase 1 only)
    __shared__ __align__(16) signed char v8s[128*144];  // [d][t] int8 (transposed)
    __shared__ __align__(16) signed char pcs[64*144];   // [q][t] code' int8
    __shared__ float rs_c1[64], rs_c2[64], rs_c3[64];
    __shared__ float rs_mx[64], rs_den[64], rs_mn[64];
    __shared__ float rs_u1[64], rs_w1[64], rs_psc[64], rs_pmn[64];
    __shared__ float ktA[128], ktB[128], ktC[128];      // ks*S2, km*S2, sk8
    __shared__ float vsA[128], vsB[128];                // vs, vm (current group)
    __shared__ float vsumL[128], cgsL[128];             // in-block VSUM / CGS row

    const int tid  = threadIdx.x;
    const int w    = tid >> 6;
    const int lane = tid & 63;
    const int n    = lane & 15;
    const int quad = lane >> 4;
    const int bhi  = blockIdx.x & 31;
    const int qt   = 31 - (int)(blockIdx.x >> 5);   // heavy tiles first
    const int b    = bhi >> 4, h = bhi & 15;
    const int causal = *CAUSAL;
    const int s0   = qt * 64;
    const int boff = b*2048 + h*128;
    const v4i vzero = {0,0,0,0};
    const v4i ones  = {0x01010101,0x01010101,0x01010101,0x01010101};

    // ---- stage Q tile (float -> int8 LDS) + per-row consts ----
    #pragma unroll
    for (int it = 0; it < 8; ++it) {
        int idx = tid + it*256;
        int row = idx >> 5, d4 = (idx & 31) << 2;
        float4 x = *(const float4*)(Q + (size_t)(s0+row)*RSTR + boff + d4);
        int a=(int)x.x, b2=(int)x.y, c=(int)x.z, d=(int)x.w;
        *(int*)(q8s + row*144 + d4) = (a&255)|((b2&255)<<8)|((c&255)<<16)|((d&255)<<24);
    }
    if (tid < 64) {
        int si = (s0 + tid)*32 + bhi;
        rs_c1[tid] = QSC[si]; rs_c2[tid] = QMN[si];
    }
    __syncthreads();

    const int kt_end = causal ? ((s0 + 63) >> 7) : 15;

    v4i a0p = *(const v4i*)(q8s + (16*w + n)*144 + 16*quad);
    v4i a1p = *(const v4i*)(q8s + (16*w + n)*144 + 64 + 16*quad);

    // Q token sums via one MFMA-ones pair -> rs_c3 (prep never reads Q)
    {
        v4i qsum = MFMA16(a0p, ones, vzero);
        qsum = MFMA16(a1p, ones, qsum);
        if (n == 0) {
            #pragma unroll
            for (int r = 0; r < 4; ++r) {
                int qq = 16*w + 4*quad + r;
                rs_c3[qq] = fmaf(rs_c1[qq], (float)qsum[r], 128.0f*rs_c2[qq]);
            }
        }
    }
    __syncthreads();

    float c1r[4], c2r[4], c3r[4]; int qgr[4];
    #pragma unroll
    for (int r = 0; r < 4; ++r) {
        int qq = 16*w + 4*quad + r;
        c1r[r] = rs_c1[qq]; c2r[r] = rs_c2[qq]; c3r[r] = rs_c3[qq];
        qgr[r] = s0 + qq;
    }

    float m[4], l[4], mn[4];
    #pragma unroll
    for (int r = 0; r < 4; ++r) { m[r] = -INFINITY; l[r] = 0.f; mn[r] = INFINITY; }

    // ================= Phase 1: softmax stats (log2 domain) =================
    // R11 2-barrier staged form; DOMN compile-time-splits fmin tracking.
#define P1_TILE(MASKED, DOMN)                                                    \
  do {                                                                           \
    const int t0g = kt * 128;                                                    \
    __syncthreads();                                                             \
    _Pragma("unroll")                                                            \
    for (int it = 0; it < 4; ++it) {                                             \
        int idx = tid + it*256;                                                  \
        int trow = idx >> 3, doff = (idx & 7) << 4;                              \
        *(uint4*)(k8s + trow*144 + doff) =                                       \
            *(const uint4*)(K8 + ((size_t)(t0g+trow)*32 + bhi)*128 + doff);      \
    }                                                                            \
    if (tid < 128) {                                                             \
        int si = (t0g + tid)*32 + bhi;                                           \
        ktA[tid] = KSC[si]*SCALE2; ktB[tid] = KMN[si]*SCALE2; ktC[tid] = SKs[si];\
    }                                                                            \
    __syncthreads();                                                             \
    float tmax[4], sarr[8][4];                                                   \
    _Pragma("unroll")                                                            \
    for (int r = 0; r < 4; ++r) tmax[r] = -INFINITY;                             \
    _Pragma("unroll")                                                            \
    for (int tb = 0; tb < 8; ++tb) {                                             \
        v4i b0 = *(const v4i*)(k8s + (16*tb + n)*144 + 16*quad);                 \
        v4i b1 = *(const v4i*)(k8s + (16*tb + n)*144 + 64 + 16*quad);            \
        v4i acc = MFMA16(a0p, b0, vzero);                                        \
        acc = MFMA16(a1p, b1, acc);                                              \
        int tl = 16*tb + n;                                                      \
        float kA = ktA[tl], kB = ktB[tl], kC = ktC[tl];                          \
        _Pragma("unroll")                                                        \
        for (int r = 0; r < 4; ++r) {                                            \
            float Sf = (float)acc[r];                                            \
            float sv = fmaf(kA, fmaf(c1r[r], Sf, c2r[r]*kC), kB*c3r[r]);         \
            if (MASKED) sv = (t0g + tl > qgr[r]) ? -INFINITY : sv;               \
            sarr[tb][r] = sv;                                                    \
            tmax[r] = fmaxf(tmax[r], sv);                                        \
            if (DOMN) mn[r] = fminf(mn[r], sv);                                  \
        }                                                                        \
    }                                                                            \
    _Pragma("unroll")                                                            \
    for (int r = 0; r < 4; ++r) {                                                \
        float mm = fmaxf(m[r], tmax[r]);                                         \
        if (mm > -INFINITY) {                                                    \
            float e0 = EXP2F(sarr[0][r]-mm) + EXP2F(sarr[1][r]-mm);              \
            float e1 = EXP2F(sarr[2][r]-mm) + EXP2F(sarr[3][r]-mm);              \
            float e2 = EXP2F(sarr[4][r]-mm) + EXP2F(sarr[5][r]-mm);              \
            float e3 = EXP2F(sarr[6][r]-mm) + EXP2F(sarr[7][r]-mm);              \
            l[r] = fmaf(l[r], EXP2F(m[r]-mm), (e0+e1)+(e2+e3));                  \
            m[r] = mm;                                                           \
        }                                                                        \
    }                                                                            \
  } while (0)

    if ((!causal) || (qt == 31)) {
        int kt;
        for (kt = 0; kt < kt_end; ++kt) P1_TILE(false, true);
        kt = kt_end;
        if (causal) P1_TILE(true, true); else P1_TILE(false, true);
    } else {
        int kt;
        for (kt = 0; kt < kt_end; ++kt) P1_TILE(false, false);
        kt = kt_end;
        P1_TILE(true, false);
    }

    // reduce stats across the 16 col-lanes
    #pragma unroll
    for (int r = 0; r < 4; ++r) {
        #pragma unroll
        for (int off = 1; off < 16; off <<= 1) {
            float m2 = __shfl_xor(m[r], off);
            float l2 = __shfl_xor(l[r], off);
            float n2 = __shfl_xor(mn[r], off);
            float mm = fmaxf(m[r], m2);
            if (mm > -INFINITY) l[r] = l[r]*EXP2F(m[r]-mm) + l2*EXP2F(m2-mm);
            m[r] = mm;
            mn[r] = fminf(mn[r], n2);
        }
        if (n == 0) {
            int qq = 16*w + 4*quad + r;
            rs_mx[qq] = m[r]; rs_den[qq] = l[r]; rs_mn[qq] = mn[r];
        }
    }
    __syncthreads();
    if (tid < 64) {
        float mx = rs_mx[tid], den = rs_den[tid], mnv = rs_mn[tid];
        float invd = 1.0f/den;
        int s = s0 + tid;
        bool hasmask = (causal != 0) && (s < S_LEN-1);
        float pmin = hasmask ? 0.0f : EXP2F(mnv - mx)*invd;
        float psc  = (invd - pmin)/255.0f + 1e-12f;
        float ipsc = 1.0f/psc;
        rs_u1[tid] = invd*ipsc; rs_w1[tid] = -pmin*ipsc;
        rs_psc[tid] = psc; rs_pmn[tid] = pmin;
    } else if (tid >= 128) {
        // in-block VSUM (full row) + CGS (cumulative to kt_end) for this bh
        int d = tid - 128;
        float vsum = 0.f, cgs = 0.f;
        #pragma unroll
        for (int g = 0; g < 16; ++g) {
            float gs = GSV[((size_t)bhi*16 + g)*128 + d];
            int vi = ((g*BATCH + b)*NH + h)*HD + d;
            float vs = VSC[vi], vm = VMN[vi];
            vsum = fmaf(vs, gs, fmaf(128.0f, vm, vsum));
            if (g <= kt_end) cgs = fmaf(128.0f*vs, gs, fmaf(16384.0f, vm, cgs));
        }
        vsumL[d] = vsum; cgsL[d] = cgs;
    }
    __syncthreads();

    // ---- hoist P2 tile-invariants: Q B-fragments + per-q constants ----
    v4i qb0[4], qb1[4];
    float qc1[4], qc2[4], qc3[4], qmxn[4], qu1[4], qw1[4];
    int qgq[4];
    #pragma unroll
    for (int cb = 0; cb < 4; ++cb) {
        int qcol = 16*cb + n;
        qb0[cb] = *(const v4i*)(q8s + qcol*144 + 16*quad);
        qb1[cb] = *(const v4i*)(q8s + qcol*144 + 64 + 16*quad);
        qc1[cb] = rs_c1[qcol]; qc2[cb] = rs_c2[qcol]; qc3[cb] = rs_c3[qcol];
        qmxn[cb] = -rs_mx[qcol]; qu1[cb] = rs_u1[qcol]; qw1[cb] = rs_w1[qcol];
        qgq[cb] = s0 + qcol;
    }

    // ================= Phase 2: requant + PV =================
    float outa[4][8];
    #pragma unroll
    for (int r = 0; r < 4; ++r)
        #pragma unroll
        for (int db = 0; db < 8; ++db) outa[r][db] = 0.f;

#define P2_TILE(MASKED)                                                          \
  do {                                                                           \
    const int t0g = kt * 128;                                                    \
    __syncthreads();   /* previous PV reads of v8s/pcs done */                   \
    _Pragma("unroll")                                                            \
    for (int it = 0; it < 4; ++it) {                                             \
        int idx = tid + it*256;                                                  \
        int trow = idx >> 3, doff = (idx & 7) << 4;                              \
        *(uint4*)(v8s + trow*144 + doff) =                                       \
            *(const uint4*)(V8T + ((size_t)bhi*128 + trow)*2048 + t0g + doff);   \
    }                                                                            \
    if (tid < 128) {                                                             \
        int si = (t0g + tid)*32 + bhi;                                           \
        ktA[tid] = KSC[si]*SCALE2; ktB[tid] = KMN[si]*SCALE2; ktC[tid] = SKs[si];\
    } else {                                                                     \
        int d = tid - 128;                                                       \
        int vi = ((kt*BATCH + b)*NH + h)*HD + d;                                 \
        vsA[d] = VSC[vi]; vsB[d] = VMN[vi];                                      \
    }                                                                            \
    __syncthreads();                                                             \
    _Pragma("unroll")                                                            \
    for (int rb = 0; rb < 2; ++rb) {                                             \
        int trow = 32*w + 16*rb;                                                 \
        const signed char* kp = K8 + ((size_t)(t0g+trow+n)*32 + bhi)*128         \
                                   + 16*quad;                                    \
        v4i a0 = *(const v4i*)kp;          /* A-operand direct from global */    \
        v4i a1 = *(const v4i*)(kp + 64);                                         \
        float ksr[4], kmr[4], skr[4];                                            \
        int tgb = t0g + trow + 4*quad;                                           \
        _Pragma("unroll")                                                        \
        for (int r = 0; r < 4; ++r) {                                            \
            int tl = trow + 4*quad + r;                                          \
            ksr[r] = ktA[tl]; kmr[r] = ktB[tl]; skr[r] = ktC[tl];                \
        }                                                                        \
        _Pragma("unroll")                                                        \
        for (int cb = 0; cb < 4; ++cb) {                                         \
            v4i acc = MFMA16(a0, qb0[cb], vzero);                                \
            acc = MFMA16(a1, qb1[cb], acc);                                      \
            int cby[4];                                                          \
            _Pragma("unroll")                                                    \
            for (int r = 0; r < 4; ++r) {                                        \
                float Sf = (float)acc[r];                                        \
                float x = fmaf(ksr[r], fmaf(qc1[cb], Sf, qc2[cb]*skr[r]),        \
                               fmaf(kmr[r], qc3[cb], qmxn[cb]));                 \
                if (MASKED) x = (tgb + r > qgq[cb]) ? -INFINITY : x;             \
                float e = EXP2F(x);                                              \
                float f = fmaf(e, qu1[cb], qw1[cb]) + 8388608.0f; /* RNE int */  \
                cby[r] = __float_as_int(f);                                      \
            }                                                                    \
            unsigned t01 = __builtin_amdgcn_perm((unsigned)cby[1],               \
                                                 (unsigned)cby[0], 0x00000400u); \
            unsigned t23 = __builtin_amdgcn_perm((unsigned)cby[3],               \
                                                 (unsigned)cby[2], 0x04000000u); \
            int packed = (int)(__builtin_amdgcn_perm(t23, t01, 0x07060100u)      \
                               ^ 0x80808080u);  /* code - 128 per byte */        \
            *(int*)(pcs + (16*cb + n)*144 + trow + 4*quad) = packed;             \
        }                                                                        \
    }                                                                            \
    __syncthreads();                                                             \
    {                                                                            \
        v4i a0 = *(const v4i*)(pcs + (16*w + n)*144 + 16*quad);                  \
        v4i a1 = *(const v4i*)(pcs + (16*w + n)*144 + 64 + 16*quad);             \
        v4i c1a = MFMA16(a0, ones, vzero);                                       \
        c1a = MFMA16(a1, ones, c1a);                                             \
        float c1f[4];                                                            \
        _Pragma("unroll")                                                        \
        for (int r = 0; r < 4; ++r) c1f[r] = (float)c1a[r];                      \
        _Pragma("unroll")                                                        \
        for (int db = 0; db < 8; ++db) {                                         \
            v4i b0 = *(const v4i*)(v8s + (16*db + n)*144 + 16*quad);             \
            v4i b1 = *(const v4i*)(v8s + (16*db + n)*144 + 64 + 16*quad);        \
            v4i cv = MFMA16(a0, b0, vzero);                                      \
            cv = MFMA16(a1, b1, cv);                                             \
            int d = 16*db + n;                                                   \
            float vs = vsA[d], vm = vsB[d];                                      \
            _Pragma("unroll")                                                    \
            for (int r = 0; r < 4; ++r)                                          \
                outa[r][db] = fmaf(vs, (float)cv[r],                             \
                                   fmaf(vm, c1f[r], outa[r][db]));               \
        }                                                                        \
    }                                                                            \
  } while (0)

    {
        int kt;
        for (kt = 0; kt < kt_end; ++kt) P2_TILE(false);
        kt = kt_end;
        if (causal) P2_TILE(true); else P2_TILE(false);
    }

    // ---- epilogue: out = psc*(outa + cgs) + pmin*vsum ----
    float pscr[4], pmnr[4];
    #pragma unroll
    for (int r = 0; r < 4; ++r) {
        int qq = 16*w + 4*quad + r;
        pscr[r] = rs_psc[qq]; pmnr[r] = rs_pmn[qq];
    }
    #pragma unroll
    for (int db = 0; db < 8; ++db) {
        int d = 16*db + n;
        float vsum = vsumL[d];
        float cgs  = cgsL[d];
        #pragma unroll
        for (int r = 0; r < 4; ++r) {
            int s = s0 + 16*w + 4*quad + r;
            OUT[(size_t)s*RSTR + boff + d] = fmaf(pscr[r], outa[r][db] + cgs, pmnr[r]*vsum);
        }
    }
}

extern "C" void kernel_launch(void* const* d_in, const int* in_sizes, int n_in,
                              void* d_out, int out_size, void* d_ws, size_t ws_size,
                              hipStream_t stream) {
    (void)in_sizes; (void)n_in; (void)out_size; (void)ws_size;
    const float* Q   = (const float*)d_in[0];
    const float* K   = (const float*)d_in[1];
    const float* V   = (const float*)d_in[2];
    const float* QMN = (const float*)d_in[3];
    const float* QSC = (const float*)d_in[4];
    const float* KMN = (const float*)d_in[5];
    const float* KSC = (const float*)d_in[6];
    const float* VMN = (const float*)d_in[7];
    const float* VSC = (const float*)d_in[8];
    const int*   CS  = (const int*)d_in[9];
    float* out = (float*)d_out;

    char* ws = (char*)d_ws;
    signed char* K8  = (signed char*)(ws + WS_K8);
    signed char* V8T = (signed char*)(ws + WS_V8T);
    float* SKs  = (float*)(ws + WS_SK);
    float* GSVp = (float*)(ws + WS_GSV);

    prep<<<1536, 256, 0, stream>>>(K, V, K8, SKs, V8T, GSVp);
    attn_main<<<1024, 256, 0, stream>>>(Q, K8, V8T, QMN, QSC, KMN, KSC, VMN, VSC,
                                        SKs, GSVp, CS, out);
}

// Round 9
// 235.104 us; speedup vs baseline: 1.0947x; 1.0145x over previous
//
#include <hip/hip_runtime.h>
#include <math.h>

// Quantized causal attention on int8 MFMA — R15.
// R14 post-mortem: 238.5us best; attn ~120 at 2 blocks/CU (register wall,
// confirmed 4x). Bank-conflict lever discarded on theory: all LDS patterns
// at stride 144B distribute 8 lanes/4-bank-group, consecutive-8 disjoint
// (= b128 phasing minimum); counter is bit-identical every round -> counts
// inherent phasing, not contention. DOMN split dropped (no measured delta).
// R15 = R14 with ONE change: P1 processes K-tile PAIRS.
//  - Stage 256 t-rows + 256 consts per burst (8 b128 stores, all 256 thr),
//    then compute two tiles back-to-back. P1 barriers 32 -> ~17/block.
//    Longer compute per stage event = better cross-block phase coverage
//    (the only hiding mechanism that has worked; R13 showed intra-wave
//    prefetch hurts, R7/R9/R12 showed more blocks spill).
//  - LDS: pair buffer un[256*144]=36.9KB aliases P2's v8s+pcs (27.6KB);
//    total ~53.8KB -> still 2 blocks/CU. Register shape identical.
//  - P2 = R14 verbatim (every P2 modification has lost).
// Tripwires: WRITE_SIZE >= 40MB = spill -> revert; attn >= 122us = pairing
// refuted -> R14 is the floor of this structure.

#define S_LEN 2048
#define BATCH 2
#define NH    16
#define HD    128
#define RSTR  4096   // floats between seq positions
#define SCALE2 (0.08838834764831845f * 1.4426950408889634f)   // (1/sqrt(128))/ln2
#define EXP2F(x) __builtin_amdgcn_exp2f(x)

typedef int v4i __attribute__((ext_vector_type(4)));
#define MFMA16(a,b,c) __builtin_amdgcn_mfma_i32_16x16x64_i8((a),(b),(c),0,0,0)

// ws byte offsets
#define WS_K8   0u
#define WS_V8T  (8u*1024u*1024u)
#define WS_SK   (16u*1024u*1024u)
#define WS_GSV  (WS_SK + 256u*1024u)

__device__ __forceinline__ int sbsum(unsigned p) {
    return (int)(signed char)(p) + (int)(signed char)(p>>8)
         + (int)(signed char)(p>>16) + (int)(signed char)(p>>24);
}

// ---- fused prep: V transpose+GSV (blocks 0..511, heavy, first) ----
// ----             K pack+SKs       (blocks 512..1535)             ----
__global__ __launch_bounds__(256) void prep(
    const float* __restrict__ K, const float* __restrict__ V,
    signed char* __restrict__ K8, float* __restrict__ SKs,
    signed char* __restrict__ V8T, float* __restrict__ GSV)
{
    __shared__ int v8i[128*33];
    const int tid = threadIdx.x;
    const int bx  = blockIdx.x;
    if (bx >= 512) {
        const int base = (bx - 512)*2048 + tid;       // 1024 blocks x 256 x 8
        #pragma unroll
        for (int rep = 0; rep < 8; ++rep) {
            int idx = base + rep*256;                 // float4 index
            float4 x = *(const float4*)(K + (size_t)idx*4);
            int a=(int)x.x, b=(int)x.y, c=(int)x.z, d=(int)x.w;
            ((int*)K8)[idx] = (a&255)|((b&255)<<8)|((c&255)<<16)|((d&255)<<24);
            float s = x.x + x.y + x.z + x.w;
            #pragma unroll
            for (int off = 16; off >= 1; off >>= 1) s += __shfl_xor(s, off);
            if ((tid & 31) == 0) SKs[idx >> 5] = s;
        }
    } else {
        const int bid = bx;
        const int bh = bid & 31, ck = bid >> 5;   // ck = 128-t chunk = v-group
        const int b = bh >> 4, h = bh & 15;
        const int t0 = ck * 128;
        const int boff = b*2048 + h*128;
        #pragma unroll
        for (int it = 0; it < 16; ++it) {
            int idx = tid + it*256;
            int t = idx >> 5, dw = idx & 31;
            float4 x = *(const float4*)(V + (size_t)(t0+t)*RSTR + boff + 4*dw);
            int a=(int)x.x, b2=(int)x.y, c=(int)x.z, d=(int)x.w;
            v8i[t*33 + dw] = (a&255)|((b2&255)<<8)|((c&255)<<16)|((d&255)<<24);
        }
        __syncthreads();
        #pragma unroll
        for (int it = 0; it < 4; ++it) {
            int j = tid + it*256;
            int tg = j & 31, dw = j >> 5;
            unsigned r0 = (unsigned)v8i[(4*tg+0)*33 + dw];
            unsigned r1 = (unsigned)v8i[(4*tg+1)*33 + dw];
            unsigned r2 = (unsigned)v8i[(4*tg+2)*33 + dw];
            unsigned r3 = (unsigned)v8i[(4*tg+3)*33 + dw];
            unsigned x01 = __builtin_amdgcn_perm(r1, r0, 0x05010400u);
            unsigned x23 = __builtin_amdgcn_perm(r3, r2, 0x05010400u);
            unsigned y01 = __builtin_amdgcn_perm(r1, r0, 0x07030602u);
            unsigned y23 = __builtin_amdgcn_perm(r3, r2, 0x07030602u);
            unsigned p[4];
            p[0] = __builtin_amdgcn_perm(x23, x01, 0x05040100u);
            p[1] = __builtin_amdgcn_perm(x23, x01, 0x07060302u);
            p[2] = __builtin_amdgcn_perm(y23, y01, 0x05040100u);
            p[3] = __builtin_amdgcn_perm(y23, y01, 0x07060302u);
            int s[4];
            #pragma unroll
            for (int jj = 0; jj < 4; ++jj) {
                int d = 4*dw + jj;
                *(int*)(V8T + ((size_t)bh*128 + d)*2048 + t0 + 4*tg) = (int)p[jj];
                s[jj] = sbsum(p[jj]);
            }
            #pragma unroll
            for (int off = 1; off < 32; off <<= 1) {
                #pragma unroll
                for (int jj = 0; jj < 4; ++jj) s[jj] += __shfl_xor(s[jj], off);
            }
            if (tg == 0) {
                #pragma unroll
                for (int jj = 0; jj < 4; ++jj)
                    GSV[((size_t)bh*16 + ck)*128 + 4*dw + jj] = (float)s[jj];
            }
        }
    }
}

// ---- main kernel ----
__global__ __launch_bounds__(256, 2) void attn_main(
    const float* __restrict__ Q,
    const signed char* __restrict__ K8, const signed char* __restrict__ V8T,
    const float* __restrict__ QMN, const float* __restrict__ QSC,
    const float* __restrict__ KMN, const float* __restrict__ KSC,
    const float* __restrict__ VMN, const float* __restrict__ VSC,
    const float* __restrict__ SKs, const float* __restrict__ GSV,
    const int* __restrict__ CAUSAL, float* __restrict__ OUT)
{
    __shared__ __align__(16) signed char q8s[64*144];   // [q][d] int8
    __shared__ __align__(16) signed char un[256*144];   // P1: K pair [256][144] | P2: v8s+pcs
    __shared__ float rs_c1[64], rs_c2[64], rs_c3[64];
    __shared__ float rs_mx[64], rs_den[64], rs_mn[64];
    __shared__ float rs_u1[64], rs_w1[64], rs_psc[64], rs_pmn[64];
    __shared__ float ktA[256], ktB[256], ktC[256];      // ks*S2, km*S2, sk8
    __shared__ float vsA[128], vsB[128];                // vs, vm (current group)
    __shared__ float vsumL[128], cgsL[128];             // in-block VSUM / CGS row

    signed char* k8u = un;              // Phase-1 alias (K pair tile)
    signed char* v8s = un;              // Phase-2 alias (V [d][t])
    signed char* pcs = un + 128*144;    // Phase-2 alias (codes [q][t])

    const int tid  = threadIdx.x;
    const int w    = tid >> 6;
    const int lane = tid & 63;
    const int n    = lane & 15;
    const int quad = lane >> 4;
    const int bhi  = blockIdx.x & 31;
    const int qt   = 31 - (int)(blockIdx.x >> 5);   // heavy tiles first
    const int b    = bhi >> 4, h = bhi & 15;
    const int causal = *CAUSAL;
    const int s0   = qt * 64;
    const int boff = b*2048 + h*128;
    const v4i vzero = {0,0,0,0};
    const v4i ones  = {0x01010101,0x01010101,0x01010101,0x01010101};

    // ---- stage Q tile (float -> int8 LDS) + per-row consts ----
    #pragma unroll
    for (int it = 0; it < 8; ++it) {
        int idx = tid + it*256;
        int row = idx >> 5, d4 = (idx & 31) << 2;
        float4 x = *(const float4*)(Q + (size_t)(s0+row)*RSTR + boff + d4);
        int a=(int)x.x, b2=(int)x.y, c=(int)x.z, d=(int)x.w;
        *(int*)(q8s + row*144 + d4) = (a&255)|((b2&255)<<8)|((c&255)<<16)|((d&255)<<24);
    }
    if (tid < 64) {
        int si = (s0 + tid)*32 + bhi;
        rs_c1[tid] = QSC[si]; rs_c2[tid] = QMN[si];
    }
    __syncthreads();

    const int kt_end = causal ? ((s0 + 63) >> 7) : 15;

    v4i a0p = *(const v4i*)(q8s + (16*w + n)*144 + 16*quad);
    v4i a1p = *(const v4i*)(q8s + (16*w + n)*144 + 64 + 16*quad);

    // Q token sums via one MFMA-ones pair -> rs_c3 (prep never reads Q)
    {
        v4i qsum = MFMA16(a0p, ones, vzero);
        qsum = MFMA16(a1p, ones, qsum);
        if (n == 0) {
            #pragma unroll
            for (int r = 0; r < 4; ++r) {
                int qq = 16*w + 4*quad + r;
                rs_c3[qq] = fmaf(rs_c1[qq], (float)qsum[r], 128.0f*rs_c2[qq]);
            }
        }
    }
    __syncthreads();

    float c1r[4], c2r[4], c3r[4]; int qgr[4];
    #pragma unroll
    for (int r = 0; r < 4; ++r) {
        int qq = 16*w + 4*quad + r;
        c1r[r] = rs_c1[qq]; c2r[r] = rs_c2[qq]; c3r[r] = rs_c3[qq];
        qgr[r] = s0 + qq;
    }

    float m[4], l[4], mn[4];
    #pragma unroll
    for (int r = 0; r < 4; ++r) { m[r] = -INFINITY; l[r] = 0.f; mn[r] = INFINITY; }

    // ================= Phase 1: softmax stats, pair-tiles =================
    // Stage 256 t-rows + 256 consts per burst, compute 2 tiles back-to-back.
#define P1_STAGE_PAIR(KTP)                                                       \
    const int t0g = (KTP) * 256;                                                 \
    __syncthreads();                                                             \
    _Pragma("unroll")                                                            \
    for (int it = 0; it < 8; ++it) {                                             \
        int idx = tid + it*256;                                                  \
        int trow = idx >> 3, doff = (idx & 7) << 4;                              \
        *(uint4*)(k8u + trow*144 + doff) =                                       \
            *(const uint4*)(K8 + ((size_t)(t0g+trow)*32 + bhi)*128 + doff);      \
    }                                                                            \
    {                                                                            \
        int si = (t0g + tid)*32 + bhi;                                           \
        ktA[tid] = KSC[si]*SCALE2; ktB[tid] = KMN[si]*SCALE2; ktC[tid] = SKs[si];\
    }                                                                            \
    __syncthreads();

#define P1_STAGE_ONE(KT)                                                         \
    const int t0g = (KT) * 128;                                                  \
    __syncthreads();                                                             \
    _Pragma("unroll")                                                            \
    for (int it = 0; it < 4; ++it) {                                             \
        int idx = tid + it*256;                                                  \
        int trow = idx >> 3, doff = (idx & 7) << 4;                              \
        *(uint4*)(k8u + trow*144 + doff) =                                       \
            *(const uint4*)(K8 + ((size_t)(t0g+trow)*32 + bhi)*128 + doff);      \
    }                                                                            \
    if (tid < 128) {                                                             \
        int si = (t0g + tid)*32 + bhi;                                           \
        ktA[tid] = KSC[si]*SCALE2; ktB[tid] = KMN[si]*SCALE2; ktC[tid] = SKs[si];\
    }                                                                            \
    __syncthreads();

#define P1_COMP(OFS, MASKED)                                                     \
  {                                                                              \
    float tmax[4], sarr[8][4];                                                   \
    _Pragma("unroll")                                                            \
    for (int r = 0; r < 4; ++r) tmax[r] = -INFINITY;                             \
    _Pragma("unroll")                                                            \
    for (int tb = 0; tb < 8; ++tb) {                                             \
        v4i b0 = *(const v4i*)(k8u + ((OFS) + 16*tb + n)*144 + 16*quad);         \
        v4i b1 = *(const v4i*)(k8u + ((OFS) + 16*tb + n)*144 + 64 + 16*quad);    \
        v4i acc = MFMA16(a0p, b0, vzero);                                        \
        acc = MFMA16(a1p, b1, acc);                                              \
        int tl = (OFS) + 16*tb + n;                                              \
        float kA = ktA[tl], kB = ktB[tl], kC = ktC[tl];                          \
        _Pragma("unroll")                                                        \
        for (int r = 0; r < 4; ++r) {                                            \
            float Sf = (float)acc[r];                                            \
            float sv = fmaf(kA, fmaf(c1r[r], Sf, c2r[r]*kC), kB*c3r[r]);         \
            if (MASKED) sv = (t0g + tl > qgr[r]) ? -INFINITY : sv;               \
            sarr[tb][r] = sv;                                                    \
            tmax[r] = fmaxf(tmax[r], sv);                                        \
            mn[r] = fminf(mn[r], sv);                                            \
        }                                                                        \
    }                                                                            \
    _Pragma("unroll")                                                            \
    for (int r = 0; r < 4; ++r) {                                                \
        float mm = fmaxf(m[r], tmax[r]);                                         \
        if (mm > -INFINITY) {                                                    \
            float e0 = EXP2F(sarr[0][r]-mm) + EXP2F(sarr[1][r]-mm);              \
            float e1 = EXP2F(sarr[2][r]-mm) + EXP2F(sarr[3][r]-mm);              \
            float e2 = EXP2F(sarr[4][r]-mm) + EXP2F(sarr[5][r]-mm);              \
            float e3 = EXP2F(sarr[6][r]-mm) + EXP2F(sarr[7][r]-mm);              \
            l[r] = fmaf(l[r], EXP2F(m[r]-mm), (e0+e1)+(e2+e3));                  \
            m[r] = mm;                                                           \
        }                                                                        \
    }                                                                            \
  }

    {
        const int T = kt_end + 1;                       // tiles to process
        const int fullp = (T & 1) ? (T >> 1) : ((T >> 1) - 1);
        for (int ktp = 0; ktp < fullp; ++ktp) {
            P1_STAGE_PAIR(ktp);
            P1_COMP(0, false);
            P1_COMP(128, false);
        }
        if (T & 1) {                                    // leftover single tile
            P1_STAGE_ONE(kt_end);
            if (causal) { P1_COMP(0, true); } else { P1_COMP(0, false); }
        } else {                                        // final pair, 2nd masked
            P1_STAGE_PAIR(fullp);
            P1_COMP(0, false);
            if (causal) { P1_COMP(128, true); } else { P1_COMP(128, false); }
        }
    }

    // reduce stats across the 16 col-lanes
    #pragma unroll
    for (int r = 0; r < 4; ++r) {
        #pragma unroll
        for (int off = 1; off < 16; off <<= 1) {
            float m2 = __shfl_xor(m[r], off);
            float l2 = __shfl_xor(l[r], off);
            float n2 = __shfl_xor(mn[r], off);
            float mm = fmaxf(m[r], m2);
            if (mm > -INFINITY) l[r] = l[r]*EXP2F(m[r]-mm) + l2*EXP2F(m2-mm);
            m[r] = mm;
            mn[r] = fminf(mn[r], n2);
        }
        if (n == 0) {
            int qq = 16*w + 4*quad + r;
            rs_mx[qq] = m[r]; rs_den[qq] = l[r]; rs_mn[qq] = mn[r];
        }
    }
    __syncthreads();   // all P1 reads of un done before P2 overwrites
    if (tid < 64) {
        float mx = rs_mx[tid], den = rs_den[tid], mnv = rs_mn[tid];
        float invd = 1.0f/den;
        int s = s0 + tid;
        bool hasmask = (causal != 0) && (s < S_LEN-1);
        float pmin = hasmask ? 0.0f : EXP2F(mnv - mx)*invd;
        float psc  = (invd - pmin)/255.0f + 1e-12f;
        float ipsc = 1.0f/psc;
        rs_u1[tid] = invd*ipsc; rs_w1[tid] = -pmin*ipsc;
        rs_psc[tid] = psc; rs_pmn[tid] = pmin;
    } else if (tid >= 128) {
        // in-block VSUM (full row) + CGS (cumulative to kt_end) for this bh
        int d = tid - 128;
        float vsum = 0.f, cgs = 0.f;
        #pragma unroll
        for (int g = 0; g < 16; ++g) {
            float gs = GSV[((size_t)bhi*16 + g)*128 + d];
            int vi = ((g*BATCH + b)*NH + h)*HD + d;
            float vs = VSC[vi], vm = VMN[vi];
            vsum = fmaf(vs, gs, fmaf(128.0f, vm, vsum));
            if (g <= kt_end) cgs = fmaf(128.0f*vs, gs, fmaf(16384.0f, vm, cgs));
        }
        vsumL[d] = vsum; cgsL[d] = cgs;
    }
    __syncthreads();

    // ---- hoist P2 tile-invariants: Q B-fragments + per-q constants ----
    v4i qb0[4], qb1[4];
    float qc1[4], qc2[4], qc3[4], qmxn[4], qu1[4], qw1[4];
    int qgq[4];
    #pragma unroll
    for (int cb = 0; cb < 4; ++cb) {
        int qcol = 16*cb + n;
        qb0[cb] = *(const v4i*)(q8s + qcol*144 + 16*quad);
        qb1[cb] = *(const v4i*)(q8s + qcol*144 + 64 + 16*quad);
        qc1[cb] = rs_c1[qcol]; qc2[cb] = rs_c2[qcol]; qc3[cb] = rs_c3[qcol];
        qmxn[cb] = -rs_mx[qcol]; qu1[cb] = rs_u1[qcol]; qw1[cb] = rs_w1[qcol];
        qgq[cb] = s0 + qcol;
    }

    // ================= Phase 2: requant + PV (R14 verbatim) =================
    float outa[4][8];
    #pragma unroll
    for (int r = 0; r < 4; ++r)
        #pragma unroll
        for (int db = 0; db < 8; ++db) outa[r][db] = 0.f;

#define P2_TILE(MASKED)                                                          \
  do {                                                                           \
    const int t0g = kt * 128;                                                    \
    __syncthreads();   /* previous PV reads of v8s/pcs done */                   \
    _Pragma("unroll")                                                            \
    for (int it = 0; it < 4; ++it) {                                             \
        int idx = tid + it*256;                                                  \
        int trow = idx >> 3, doff = (idx & 7) << 4;                              \
        *(uint4*)(v8s + trow*144 + doff) =                                       \
            *(const uint4*)(V8T + ((size_t)bhi*128 + trow)*2048 + t0g + doff);   \
    }                                                                            \
    if (tid < 128) {                                                             \
        int si = (t0g + tid)*32 + bhi;                                           \
        ktA[tid] = KSC[si]*SCALE2; ktB[tid] = KMN[si]*SCALE2; ktC[tid] = SKs[si];\
    } else {                                                                     \
        int d = tid - 128;                                                       \
        int vi = ((kt*BATCH + b)*NH + h)*HD + d;                                 \
        vsA[d] = VSC[vi]; vsB[d] = VMN[vi];                                      \
    }                                                                            \
    __syncthreads();                                                             \
    _Pragma("unroll")                                                            \
    for (int rb = 0; rb < 2; ++rb) {                                             \
        int trow = 32*w + 16*rb;                                                 \
        const signed char* kp = K8 + ((size_t)(t0g+trow+n)*32 + bhi)*128         \
                                   + 16*quad;                                    \
        v4i a0 = *(const v4i*)kp;          /* A-operand direct from global */    \
        v4i a1 = *(const v4i*)(kp + 64);                                         \
        float ksr[4], kmr[4], skr[4];                                            \
        int tgb = t0g + trow + 4*quad;                                           \
        _Pragma("unroll")                                                        \
        for (int r = 0; r < 4; ++r) {                                            \
            int tl = trow + 4*quad + r;                                          \
            ksr[r] = ktA[tl]; kmr[r] = ktB[tl]; skr[r] = ktC[tl];                \
        }                                                                        \
        _Pragma("unroll")                                                        \
        for (int cb = 0; cb < 4; ++cb) {                                         \
            v4i acc = MFMA16(a0, qb0[cb], vzero);                                \
            acc = MFMA16(a1, qb1[cb], acc);                                      \
            int cby[4];                                                          \
            _Pragma("unroll")                                                    \
            for (int r = 0; r < 4; ++r) {                                        \
                float Sf = (float)acc[r];                                        \
                float x = fmaf(ksr[r], fmaf(qc1[cb], Sf, qc2[cb]*skr[r]),        \
                               fmaf(kmr[r], qc3[cb], qmxn[cb]));                 \
                if (MASKED) x = (tgb + r > qgq[cb]) ? -INFINITY : x;             \
                float e = EXP2F(x);                                              \
                float f = fmaf(e, qu1[cb], qw1[cb]) + 8388608.0f; /* RNE int */  \
                cby[r] = __float_as_int(f);                                      \
            }                                                                    \
            unsigned t01 = __builtin_amdgcn_perm((unsigned)cby[1],               \
                                                 (unsigned)cby[0], 0x00000400u); \
            unsigned t23 = __builtin_amdgcn_perm((unsigned)cby[3],               \
                                                 (unsigned)cby[2], 0x04000000u); \
            int packed = (int)(__builtin_amdgcn_perm(t23, t01, 0x07060100u)      \
                               ^ 0x80808080u);  /* code - 128 per byte */        \
            *(int*)(pcs + (16*cb + n)*144 + trow + 4*quad) = packed;             \
        }                                                                        \
    }                                                                            \
    __syncthreads();                                                             \
    {                                                                            \
        v4i a0 = *(const v4i*)(pcs + (16*w + n)*144 + 16*quad);                  \
        v4i a1 = *(const v4i*)(pcs + (16*w + n)*144 + 64 + 16*quad);             \
        v4i c1a = MFMA16(a0, ones, vzero);                                       \
        c1a = MFMA16(a1, ones, c1a);                                             \
        float c1f[4];                                                            \
        _Pragma("unroll")                                                        \
        for (int r = 0; r < 4; ++r) c1f[r] = (float)c1a[r];                      \
        _Pragma("unroll")                                                        \
        for (int db = 0; db < 8; ++db) {                                         \
            v4i b0 = *(const v4i*)(v8s + (16*db + n)*144 + 16*quad);             \
            v4i b1 = *(const v4i*)(v8s + (16*db + n)*144 + 64 + 16*quad);        \
            v4i cv = MFMA16(a0, b0, vzero);                                      \
            cv = MFMA16(a1, b1, cv);                                             \
            int d = 16*db + n;                                                   \
            float vs = vsA[d], vm = vsB[d];                                      \
            _Pragma("unroll")                                                    \
            for (int r = 0; r < 4; ++r)                                          \
                outa[r][db] = fmaf(vs, (float)cv[r],                             \
                                   fmaf(vm, c1f[r], outa[r][db]));               \
        }                                                                        \
    }                                                                            \
  } while (0)

    {
        int kt;
        for (kt = 0; kt < kt_end; ++kt) P2_TILE(false);
        kt = kt_end;
        if (causal) P2_TILE(true); else P2_TILE(false);
    }

    // ---- epilogue: out = psc*(outa + cgs) + pmin*vsum ----
    float pscr[4], pmnr[4];
    #pragma unroll
    for (int r = 0; r < 4; ++r) {
        int qq = 16*w + 4*quad + r;
        pscr[r] = rs_psc[qq]; pmnr[r] = rs_pmn[qq];
    }
    #pragma unroll
    for (int db = 0; db < 8; ++db) {
        int d = 16*db + n;
        float vsum = vsumL[d];
        float cgs  = cgsL[d];
        #pragma unroll
        for (int r = 0; r < 4; ++r) {
            int s = s0 + 16*w + 4*quad + r;
            OUT[(size_t)s*RSTR + boff + d] = fmaf(pscr[r], outa[r][db] + cgs, pmnr[r]*vsum);
        }
    }
}

extern "C" void kernel_launch(void* const* d_in, const int* in_sizes, int n_in,
                              void* d_out, int out_size, void* d_ws, size_t ws_size,
                              hipStream_t stream) {
    (void)in_sizes; (void)n_in; (void)out_size; (void)ws_size;
    const float* Q   = (const float*)d_in[0];
    const float* K   = (const float*)d_in[1];
    const float* V   = (const float*)d_in[2];
    const float* QMN = (const float*)d_in[3];
    const float* QSC = (const float*)d_in[4];
    const float* KMN = (const float*)d_in[5];
    const float* KSC = (const float*)d_in[6];
    const float* VMN = (const float*)d_in[7];
    const float* VSC = (const float*)d_in[8];
    const int*   CS  = (const int*)d_in[9];
    float* out = (float*)d_out;

    char* ws = (char*)d_ws;
    signed char* K8  = (signed char*)(ws + WS_K8);
    signed char* V8T = (signed char*)(ws + WS_V8T);
    float* SKs  = (float*)(ws + WS_SK);
    float* GSVp = (float*)(ws + WS_GSV);

    prep<<<1536, 256, 0, stream>>>(K, V, K8, SKs, V8T, GSVp);
    attn_main<<<1024, 256, 0, stream>>>(Q, K8, V8T, QMN, QSC, KMN, KSC, VMN, VSC,
                                        SKs, GSVp, CS, out);
}